// Round 11
// baseline (1499.055 us; speedup 1.0000x reference)
//
#include <hip/hip_runtime.h>
#include <hip/hip_bf16.h>
#include <math.h>

#define BGR   8192        // graphs
#define NND   9           // nodes per graph
#define BN    73728       // BGR*NND
#define NE    131072      // BGR*16 explicit edges
#define H     128
#define MH    256
#define FIN   15

typedef __bf16 bf16_t;
typedef bf16_t bf16x8 __attribute__((ext_vector_type(8)));
typedef float  f32x4  __attribute__((ext_vector_type(4)));
typedef float  f32x16 __attribute__((ext_vector_type(16)));

__device__ __forceinline__ unsigned short f2bf(float f) {
    unsigned int u = __float_as_uint(f);
    u += 0x7fff + ((u >> 16) & 1);           // RNE (inputs are finite)
    return (unsigned short)(u >> 16);
}
__device__ __forceinline__ unsigned int pkbf(float a, float b) {
    union { __hip_bfloat162 h; unsigned int u; } un;
    un.h = __float22bfloat162_rn(make_float2(a, b));
    return un.u;
}
__device__ __forceinline__ bf16x8 as_frag(int4 v) {
    union { int4 i; bf16x8 f; } u; u.i = v; return u.f;
}
__device__ __forceinline__ float fast_tanh(float v) {
    float e = __expf(2.0f * v);
    return 1.0f - __fdividef(2.0f, e + 1.0f);
}
// 16-deep XOR swizzle, K=256 row (32x32 fragments, 2 lanes/bank = free)
__device__ __forceinline__ int sw16(int m, int k) {
    return m * 256 + ((((k >> 3) ^ (m & 15)) << 3) | (k & 7));
}
// 16-deep XOR swizzle, K=128 row (proj staging)
__device__ __forceinline__ int swp(int m, int k) {
    return m * 128 + ((((k >> 3) ^ (m & 15)) << 3) | (k & 7));
}
// legacy 8-deep swizzle (16x16 kernels: gru, dec)
__device__ __forceinline__ int sw_off(int m, int k) {
    return m * 256 + ((((k >> 3) ^ (m & 7)) << 3) | (k & 7));
}

// ---------------------------------------------------------------- deg kernel
__global__ void deg_kernel(const int* __restrict__ edges, float* __restrict__ inv_deg) {
    int g = blockIdx.x * 256 + threadIdx.x;
    if (g >= BGR) return;
    int cnt[NND];
#pragma unroll
    for (int n = 0; n < NND; ++n) cnt[n] = 1;   // self loop
    for (int j = 0; j < 16; ++j) {
        int d = edges[g * 32 + 16 + j];
#pragma unroll
        for (int n = 0; n < NND; ++n) cnt[n] += (d == n) ? 1 : 0;
    }
#pragma unroll
    for (int n = 0; n < NND; ++n) inv_deg[g * NND + n] = 1.0f / (float)cnt[n];
}

// ---------------------------------------------------------------- encoder
__global__ void enc_kernel(const float* __restrict__ obs, const float* __restrict__ W,
                           const float* __restrict__ b, float* __restrict__ x) {
    int tid = blockIdx.x * 256 + threadIdx.x;     // BN*128 threads
    int i = tid >> 7, h = tid & 127;
    float acc = b[h];
#pragma unroll
    for (int k = 0; k < FIN; ++k) acc += obs[i * FIN + k] * W[k * H + h];
    x[i * H + h] = tanhf(acc);
}

// ---------------------------------------------------------------- weight transpose+bf16
// out: [W1T 4x256x256(unused)][W2T 4x256x256][W3T 4x128x256][WG 4x512x256]
//      [dW1T 256x128][dW2T 256x256][W1P 4x512x128]
// W1P packed col p = w*64 + side*32 + c (w=0..7): wave w holds u (side0) and v
// (side1) for output col n = w*32 + c. u = W1[k][n], v = W1[k+128][n].
__global__ void wt_kernel(const float* __restrict__ W1, const float* __restrict__ W2,
                          const float* __restrict__ W3, const float* __restrict__ Wi,
                          const float* __restrict__ Wh, const float* __restrict__ dW1,
                          const float* __restrict__ dW2, unsigned short* __restrict__ out) {
    int idx = blockIdx.x * 256 + threadIdx.x;     // 1540096 total
    float v;
    if (idx < 262144) {
        int s = idx >> 16, r = idx & 65535, n = r >> 8, k = r & 255;
        v = W1[(s << 16) + (k << 8) + n];
    } else if (idx < 524288) {
        int i2 = idx - 262144;
        int s = i2 >> 16, r = i2 & 65535, n = r >> 8, k = r & 255;
        v = W2[(s << 16) + (k << 8) + n];
    } else if (idx < 655360) {
        int i3 = idx - 524288;
        int s = i3 >> 15, r = i3 & 32767, n = r >> 8, k = r & 255;
        v = W3[(s << 15) + (k << 7) + n];
    } else if (idx < 1179648) {
        int i4 = idx - 655360;                    // 0..524287
        int s = i4 >> 17, rr = i4 & 131071;
        int p = rr >> 8, k = rr & 255;
        int w = p >> 6, rem = p & 63;
        int gate = rem >> 4, c = rem & 15;
        int h = w * 16 + c;
        const int sb = s * 49152;                 // 128*384
        if (gate == 0)      v = (k < 128) ? Wi[sb + k * 384 + h]       : Wh[sb + (k - 128) * 384 + h];
        else if (gate == 1) v = (k < 128) ? Wi[sb + k * 384 + 128 + h] : Wh[sb + (k - 128) * 384 + 128 + h];
        else if (gate == 2) v = (k < 128) ? Wi[sb + k * 384 + 256 + h] : 0.f;
        else                v = (k < 128) ? 0.f                        : Wh[sb + (k - 128) * 384 + 256 + h];
    } else if (idx < 1212416) {
        int i5 = idx - 1179648;                   // dW1T [256][128]
        int n = i5 >> 7, k = i5 & 127;
        v = dW1[k * 256 + n];
    } else if (idx < 1277952) {
        int i6 = idx - 1212416;                   // dW2T [256][256]
        int n = i6 >> 8, k = i6 & 255;
        v = dW2[k * 256 + n];
    } else {
        int i7 = idx - 1277952;                   // W1P [s][p:512][k:128]
        int s = i7 >> 16, rr = i7 & 65535;
        int p = rr >> 7, k = rr & 127;
        int w = p >> 6, rem = p & 63;
        int side = rem >> 5, c = rem & 31;
        int n = w * 32 + c;
        v = W1[(s << 16) + ((k + side * 128) << 8) + n];
    }
    out[idx] = f2bf(v);
}

// ---------------------------------------------------------------- proj + self-message
// 64 nodes/block, 512 thr. Phase B: P = x@[U|V] (wave w holds u AND v for cols
// w*32..+32 -> act1_self thread-local). Phase C: layer2 (single-buffer). Phase D:
// layer3 -> aggr = m_self via PLAIN stores (replaces memset + self-loop atomics).
__global__ __launch_bounds__(512, 4) void proj_mfma(
        const float* __restrict__ x, const unsigned short* __restrict__ W1P,
        const float* __restrict__ b1,
        const unsigned short* __restrict__ W2T, const float* __restrict__ b2,
        const unsigned short* __restrict__ W3T,
        unsigned short* __restrict__ P, float* __restrict__ aggr) {
    __shared__ unsigned short lbuf[64 * 128];   // 16 KB
    __shared__ unsigned short abuf[64 * 256];   // 32 KB
    const int t = threadIdx.x;
    const int n0 = blockIdx.x * 64;             // node base
    const int wv = t >> 6, ln = t & 63, l31 = ln & 31, lh = ln >> 5;

    // stage bf16(x): 8 thr/row, 16 cols each
    {
        const int m = t >> 3, q = t & 7;
        const float* xs = x + (size_t)(n0 + m) * H + q * 16;
#pragma unroll
        for (int i = 0; i < 4; ++i) {
            float4 v = *(const float4*)(xs + i * 4);
            uint2 o; o.x = pkbf(v.x, v.y); o.y = pkbf(v.z, v.w);
            *(uint2*)(lbuf + swp(m, q * 16 + i * 4)) = o;
        }
    }
    __syncthreads();

    // ---- phase B: P-GEMM (u and v) + act1_self epilogue
    {
        f32x16 au[2], av[2];
#pragma unroll
        for (int a = 0; a < 2; ++a)
#pragma unroll
            for (int i = 0; i < 16; ++i) { au[a][i] = 0.f; av[a][i] = 0.f; }
        const unsigned short* wpu = W1P + (size_t)(wv * 64 + l31) * 128 + lh * 8;
        const unsigned short* wpv = W1P + (size_t)(wv * 64 + 32 + l31) * 128 + lh * 8;
#pragma unroll
        for (int ks = 0; ks < 8; ++ks) {
            const int kk = ks * 16 + lh * 8;
            bf16x8 a0 = as_frag(*(const int4*)(lbuf + swp(l31, kk)));
            bf16x8 a1 = as_frag(*(const int4*)(lbuf + swp(32 + l31, kk)));
            bf16x8 wu = as_frag(*(const int4*)(wpu + ks * 16));
            bf16x8 wvv = as_frag(*(const int4*)(wpv + ks * 16));
            au[0] = __builtin_amdgcn_mfma_f32_32x32x16_bf16(a0, wu, au[0], 0, 0, 0);
            au[1] = __builtin_amdgcn_mfma_f32_32x32x16_bf16(a1, wu, au[1], 0, 0, 0);
            av[0] = __builtin_amdgcn_mfma_f32_32x32x16_bf16(a0, wvv, av[0], 0, 0, 0);
            av[1] = __builtin_amdgcn_mfma_f32_32x32x16_bf16(a1, wvv, av[1], 0, 0, 0);
        }
        const int n = wv * 32 + l31;
        const float bias = b1[n];
#pragma unroll
        for (int mt = 0; mt < 2; ++mt)
#pragma unroll
            for (int reg = 0; reg < 16; ++reg) {
                const int mrow = mt * 32 + (reg & 3) + ((reg >> 2) << 3) + (lh << 2);
                const size_t node = n0 + mrow;
                P[node * 512 + n]       = f2bf(au[mt][reg]);
                P[node * 512 + 256 + n] = f2bf(av[mt][reg]);
                abuf[sw16(mrow, n)] = f2bf(fast_tanh(au[mt][reg] + av[mt][reg] + bias));
            }
    }
    __syncthreads();

    // ---- phase C: layer 2 (single-buffer abuf)
    {
        f32x16 acc0, acc1;
#pragma unroll
        for (int i = 0; i < 16; ++i) { acc0[i] = 0.f; acc1[i] = 0.f; }
        const unsigned short* wp = W2T + (size_t)(wv * 32 + l31) * 256 + lh * 8;
#pragma unroll
        for (int ks = 0; ks < 16; ++ks) {
            const int kk = ks * 16 + lh * 8;
            bf16x8 a0 = as_frag(*(const int4*)(abuf + sw16(l31, kk)));
            bf16x8 a1 = as_frag(*(const int4*)(abuf + sw16(32 + l31, kk)));
            bf16x8 bw = as_frag(*(const int4*)(wp + ks * 16));
            acc0 = __builtin_amdgcn_mfma_f32_32x32x16_bf16(a0, bw, acc0, 0, 0, 0);
            acc1 = __builtin_amdgcn_mfma_f32_32x32x16_bf16(a1, bw, acc1, 0, 0, 0);
        }
        __syncthreads();   // all reads of abuf done
        const int n = wv * 32 + l31;
        const float bias = b2[n];
#pragma unroll
        for (int reg = 0; reg < 16; ++reg) {
            const int mrow = (reg & 3) + ((reg >> 2) << 3) + (lh << 2);
            abuf[sw16(mrow, n)]      = f2bf(fast_tanh(acc0[reg] + bias));
            abuf[sw16(32 + mrow, n)] = f2bf(fast_tanh(acc1[reg] + bias));
        }
    }
    __syncthreads();

    // ---- phase D: layer 3 -> aggr plain store (self message, b3 deferred to GRU)
    {
        const int mt = wv & 1, nq = wv >> 1;
        const int n = nq * 32 + l31;
        f32x16 acc;
#pragma unroll
        for (int i = 0; i < 16; ++i) acc[i] = 0.f;
        const unsigned short* wp = W3T + (size_t)n * 256 + lh * 8;
#pragma unroll
        for (int ks = 0; ks < 16; ++ks) {
            const int kk = ks * 16 + lh * 8;
            bf16x8 a = as_frag(*(const int4*)(abuf + sw16(mt * 32 + l31, kk)));
            bf16x8 bw = as_frag(*(const int4*)(wp + ks * 16));
            acc = __builtin_amdgcn_mfma_f32_32x32x16_bf16(a, bw, acc, 0, 0, 0);
        }
#pragma unroll
        for (int reg = 0; reg < 16; ++reg) {
            const int m = mt * 32 + (reg & 3) + ((reg >> 2) << 3) + (lh << 2);
            aggr[(size_t)(n0 + m) * H + n] = acc[reg];
        }
    }
}

// ---------------------------------------------------------------- edge msg (layers 2-3), ZERO atomics
// 64 edges/block = 4 COMPLETE graphs (edge eg -> graph eg>>4). All in-edge
// contributions to a node are in this block: LDS ds_add reduction into aggrL
// (overlaying dead bufA), then non-atomic coalesced RMW on aggr (exclusive owner;
// proj wrote the self-message base, stream-ordered).
__global__ __launch_bounds__(512, 4) void msg_mfma(
        const unsigned short* __restrict__ P, const int* __restrict__ edges,
        const float* __restrict__ b1,
        const unsigned short* __restrict__ W2T, const float* __restrict__ b2,
        const unsigned short* __restrict__ W3T,
        float* __restrict__ aggr) {
    __shared__ unsigned short bufA[64 * 256];   // 32 KB: act1; later aggrL (f32 36x128 = 18 KB)
    __shared__ unsigned short bufB[64 * 256];   // 32 KB: act2
    __shared__ unsigned char sdstL[64];
    const int t  = threadIdx.x;
    const int e0 = blockIdx.x * 64;
    const int wv = t >> 6;
    const int ln = t & 63;
    const int l31 = ln & 31;
    const int lh  = ln >> 5;

    // ---- stage act1 = tanh(u_dst + v_src + b1); block-local dst ids
    if (t < 64) {
        const int eg = e0 + t;
        sdstL[t] = (unsigned char)(((eg >> 4) & 3) * NND + edges[(eg >> 4) * 32 + 16 + (eg & 15)]);
    }
    {
        const int row = t >> 3;          // edge slot 0..63
        const int c0  = (t & 7) * 32;
        const int eg  = e0 + row;
        const int g = eg >> 4, j = eg & 15;
        const int sn = g * NND + edges[g * 32 + j];
        const int dn = g * NND + edges[g * 32 + 16 + j];
        const unsigned short* up = P + (size_t)dn * 512 + c0;
        const unsigned short* vp = P + (size_t)sn * 512 + 256 + c0;
#pragma unroll
        for (int i = 0; i < 4; ++i) {
            const uint4 uu = *(const uint4*)(up + i * 8);
            const uint4 vv = *(const uint4*)(vp + i * 8);
            const unsigned int ua[4] = {uu.x, uu.y, uu.z, uu.w};
            const unsigned int va[4] = {vv.x, vv.y, vv.z, vv.w};
            unsigned int op[4];
#pragma unroll
            for (int j2 = 0; j2 < 4; ++j2) {
                const float2 bb = *(const float2*)(b1 + c0 + i * 8 + j2 * 2);
                const float s0 = fast_tanh(__uint_as_float(ua[j2] << 16) +
                                           __uint_as_float(va[j2] << 16) + bb.x);
                const float s1 = fast_tanh(__uint_as_float(ua[j2] & 0xffff0000u) +
                                           __uint_as_float(va[j2] & 0xffff0000u) + bb.y);
                op[j2] = pkbf(s0, s1);
            }
            *(uint4*)(bufA + sw16(row, c0 + i * 8)) = make_uint4(op[0], op[1], op[2], op[3]);
        }
    }
    __syncthreads();   // b1: act1 + sdstL visible

    // ---- layer 2: read bufA, write act2 to bufB
    {
        f32x16 acc0, acc1;
#pragma unroll
        for (int i = 0; i < 16; ++i) { acc0[i] = 0.f; acc1[i] = 0.f; }
        const unsigned short* wp = W2T + (size_t)(wv * 32 + l31) * 256 + lh * 8;
#pragma unroll
        for (int ks = 0; ks < 16; ++ks) {
            const int kk = ks * 16 + lh * 8;
            bf16x8 a0 = as_frag(*(const int4*)(bufA + sw16(l31, kk)));
            bf16x8 a1 = as_frag(*(const int4*)(bufA + sw16(32 + l31, kk)));
            bf16x8 bw = as_frag(*(const int4*)(wp + ks * 16));
            acc0 = __builtin_amdgcn_mfma_f32_32x32x16_bf16(a0, bw, acc0, 0, 0, 0);
            acc1 = __builtin_amdgcn_mfma_f32_32x32x16_bf16(a1, bw, acc1, 0, 0, 0);
        }
        const int n = wv * 32 + l31;
        const float bias = b2[n];
#pragma unroll
        for (int reg = 0; reg < 16; ++reg) {
            const int mrow = (reg & 3) + ((reg >> 2) << 3) + (lh << 2);
            bufB[sw16(mrow, n)]      = f2bf(fast_tanh(acc0[reg] + bias));
            bufB[sw16(32 + mrow, n)] = f2bf(fast_tanh(acc1[reg] + bias));
        }
    }
    __syncthreads();   // b2: bufA reads done, act2 visible

    // ---- zero aggrL (f32, 36x128, overlays bufA)
    float* aL = (float*)bufA;
#pragma unroll
    for (int i = 0; i < 9; ++i) aL[i * 512 + t] = 0.f;
    __syncthreads();   // b3: zeros visible

    // ---- layer 3: read bufB, LDS-atomic reduce into aggrL
    {
        const int mt = wv & 1, nq = wv >> 1;
        const int n = nq * 32 + l31;
        f32x16 acc;
#pragma unroll
        for (int i = 0; i < 16; ++i) acc[i] = 0.f;
        const unsigned short* wp = W3T + (size_t)n * 256 + lh * 8;
#pragma unroll
        for (int ks = 0; ks < 16; ++ks) {
            const int kk = ks * 16 + lh * 8;
            bf16x8 a = as_frag(*(const int4*)(bufB + sw16(mt * 32 + l31, kk)));
            bf16x8 bw = as_frag(*(const int4*)(wp + ks * 16));
            acc = __builtin_amdgcn_mfma_f32_32x32x16_bf16(a, bw, acc, 0, 0, 0);
        }
#pragma unroll
        for (int reg = 0; reg < 16; ++reg) {
            const int m = mt * 32 + (reg & 3) + ((reg >> 2) << 3) + (lh << 2);
            atomicAdd(&aL[(int)sdstL[m] * 128 + n], acc[reg]);
        }
    }
    __syncthreads();   // b4: reduction complete

    // ---- non-atomic RMW: this block exclusively owns its 36 nodes
    {
        float* gp = aggr + (size_t)blockIdx.x * 36 * 128;
#pragma unroll
        for (int i = 0; i < 9; ++i) {
            const int idx = i * 512 + t;     // 0..4607, coalesced
            gp[idx] += aL[idx];
        }
    }
}

// ---------------------------------------------------------------- GRU via MFMA (64 nodes / block, 512 thr)
__global__ __launch_bounds__(512, 4) void gru_mfma(
        float* __restrict__ x, float* __restrict__ aggr, const float* __restrict__ inv_deg,
        const unsigned short* __restrict__ WG, const float* __restrict__ b3m,
        const float* __restrict__ bi, const float* __restrict__ bh) {
    __shared__ unsigned short bufA[64 * 256];   // 32 KB
    const int t = threadIdx.x;
    const int n0 = blockIdx.x * 64;
    const int wv = t >> 6, ln = t & 63, lrow = ln & 15, lq = ln >> 4;

    // stage A = bf16([aggr*inv_deg + b3 | x]): m = t>>3, k-slice q*32
    {
        const int m = t >> 3;
        const int q = t & 7;
        const int k0 = q * 32;
        const int node = n0 + m;
        if (q < 4) {
            const float scale = inv_deg[node];
            const float* src = aggr + (size_t)node * H + k0;
#pragma unroll
            for (int i = 0; i < 8; ++i) {
                float4 v = *(const float4*)(src + i * 4);
                const float4 bb = *(const float4*)(b3m + k0 + i * 4);
                v.x = v.x * scale + bb.x; v.y = v.y * scale + bb.y;
                v.z = v.z * scale + bb.z; v.w = v.w * scale + bb.w;
                uint2 o; o.x = pkbf(v.x, v.y); o.y = pkbf(v.z, v.w);
                *(uint2*)(bufA + sw_off(m, k0 + i * 4)) = o;
            }
        } else {
            const float* src = x + (size_t)node * H + (k0 - 128);
#pragma unroll
            for (int i = 0; i < 8; ++i) {
                float4 v = *(const float4*)(src + i * 4);
                uint2 o; o.x = pkbf(v.x, v.y); o.y = pkbf(v.z, v.w);
                *(uint2*)(bufA + sw_off(m, k0 + i * 4)) = o;
            }
        }
    }
    __syncthreads();

    const f32x4 zero = {0.f, 0.f, 0.f, 0.f};
    f32x4 acc[4][4];    // [m-tile][gate]
#pragma unroll
    for (int i = 0; i < 4; ++i)
#pragma unroll
        for (int j = 0; j < 4; ++j) acc[i][j] = zero;

    const unsigned short* wgp = WG + (size_t)(wv * 64 + lrow) * 256;
#pragma unroll
    for (int kq = 0; kq < 8; ++kq) {
        const int ko = kq * 32 + lq * 8;
        bf16x8 af[4], bfr[4];
#pragma unroll
        for (int tm = 0; tm < 4; ++tm)
            af[tm] = as_frag(*(const int4*)(bufA + sw_off(tm * 16 + lrow, ko)));
#pragma unroll
        for (int g = 0; g < 4; ++g)
            bfr[g] = as_frag(*(const int4*)(wgp + (size_t)g * 16 * 256 + ko));
#pragma unroll
        for (int tm = 0; tm < 4; ++tm)
#pragma unroll
            for (int g = 0; g < 4; ++g)
                acc[tm][g] = __builtin_amdgcn_mfma_f32_16x16x32_bf16(af[tm], bfr[g], acc[tm][g], 0, 0, 0);
    }

    // epilogue: thread-local gate mixing for h = wv*16 + lrow
    {
        const int h = wv * 16 + lrow;
        const float b_r = bi[h] + bh[h];
        const float b_z = bi[128 + h] + bh[128 + h];
        const float b_n = bi[256 + h];
        const float b_h = bh[256 + h];
#pragma unroll
        for (int tm = 0; tm < 4; ++tm) {
#pragma unroll
            for (int r = 0; r < 4; ++r) {
                const int node = n0 + tm * 16 + lq * 4 + r;
                const float irhr = acc[tm][0][r] + b_r;
                const float izhz = acc[tm][1][r] + b_z;
                const float inn  = acc[tm][2][r] + b_n;
                const float hn   = acc[tm][3][r] + b_h;
                const float rg = 1.f / (1.f + expf(-irhr));
                const float zg = 1.f / (1.f + expf(-izhz));
                const float ng = tanhf(inn + rg * hn);
                const float xo = x[(size_t)node * H + h];
                x[(size_t)node * H + h] = (1.f - zg) * ng + zg * xo;
            }
        }
    }
}

// ---------------------------------------------------------------- decoder via MFMA (64 masked ids / block)
__global__ __launch_bounds__(256, 4) void dec_mfma(
        const float* __restrict__ x,
        const unsigned short* __restrict__ W1T, const float* __restrict__ b1,
        const unsigned short* __restrict__ W2T, const float* __restrict__ b2,
        const float* __restrict__ W3, const float* __restrict__ b3,
        float* __restrict__ out) {
    __shared__ unsigned short buf[64 * 256];   // 32 KB
    const int t = threadIdx.x;
    const int id0 = blockIdx.x * 64;
    const int wv = t >> 6, ln = t & 63, lrow = ln & 15, lq = ln >> 4;
    const int nbase = wv * 64;

    // stage bf16(x) for 64 masked ids into buf[:, 0:128]
    {
        const int m = t >> 2, q = t & 3;
        const int id = id0 + m;
        const int node = (id >> 3) * NND + (id & 7);
        const float* src = x + (size_t)node * H + q * 32;
#pragma unroll
        for (int i = 0; i < 8; ++i) {
            float4 v = *(const float4*)(src + i * 4);
            uint2 o; o.x = pkbf(v.x, v.y); o.y = pkbf(v.z, v.w);
            *(uint2*)(buf + sw_off(m, q * 32 + i * 4)) = o;
        }
    }
    __syncthreads();

    const f32x4 zero = {0.f, 0.f, 0.f, 0.f};

    // ---- layer 1: K=128 -> 256 cols
    {
        f32x4 acc[4][4];
#pragma unroll
        for (int i = 0; i < 4; ++i)
#pragma unroll
            for (int j = 0; j < 4; ++j) acc[i][j] = zero;
#pragma unroll
        for (int kq = 0; kq < 4; ++kq) {
            const int ko = kq * 32 + lq * 8;
            bf16x8 af[4], bfr[4];
#pragma unroll
            for (int tm = 0; tm < 4; ++tm)
                af[tm] = as_frag(*(const int4*)(buf + sw_off(tm * 16 + lrow, ko)));
#pragma unroll
            for (int tn = 0; tn < 4; ++tn)
                bfr[tn] = as_frag(*(const int4*)(W1T + (size_t)(nbase + tn * 16 + lrow) * 128 + ko));
#pragma unroll
            for (int tm = 0; tm < 4; ++tm)
#pragma unroll
                for (int tn = 0; tn < 4; ++tn)
                    acc[tm][tn] = __builtin_amdgcn_mfma_f32_16x16x32_bf16(af[tm], bfr[tn], acc[tm][tn], 0, 0, 0);
        }
        __syncthreads();
#pragma unroll
        for (int tn = 0; tn < 4; ++tn) {
            const int n = nbase + tn * 16 + lrow;
            const float bias = b1[n];
#pragma unroll
            for (int tm = 0; tm < 4; ++tm)
#pragma unroll
                for (int r = 0; r < 4; ++r) {
                    const int m = tm * 16 + lq * 4 + r;
                    buf[sw_off(m, n)] = f2bf(fast_tanh(acc[tm][tn][r] + bias));
                }
        }
    }
    __syncthreads();

    // ---- layer 2: K=256 -> 256 cols
    {
        f32x4 acc[4][4];
#pragma unroll
        for (int i = 0; i < 4; ++i)
#pragma unroll
            for (int j = 0; j < 4; ++j) acc[i][j] = zero;
#pragma unroll
        for (int kq = 0; kq < 8; ++kq) {
            const int ko = kq * 32 + lq * 8;
            bf16x8 af[4], bfr[4];
#pragma unroll
            for (int tm = 0; tm < 4; ++tm)
                af[tm] = as_frag(*(const int4*)(buf + sw_off(tm * 16 + lrow, ko)));
#pragma unroll
            for (int tn = 0; tn < 4; ++tn)
                bfr[tn] = as_frag(*(const int4*)(W2T + (size_t)(nbase + tn * 16 + lrow) * 256 + ko));
#pragma unroll
            for (int tm = 0; tm < 4; ++tm)
#pragma unroll
                for (int tn = 0; tn < 4; ++tn)
                    acc[tm][tn] = __builtin_amdgcn_mfma_f32_16x16x32_bf16(af[tm], bfr[tn], acc[tm][tn], 0, 0, 0);
        }
        __syncthreads();
#pragma unroll
        for (int tn = 0; tn < 4; ++tn) {
            const int n = nbase + tn * 16 + lrow;
            const float bias = b2[n];
#pragma unroll
            for (int tm = 0; tm < 4; ++tm)
#pragma unroll
                for (int r = 0; r < 4; ++r) {
                    const int m = tm * 16 + lq * 4 + r;
                    buf[sw_off(m, n)] = f2bf(fast_tanh(acc[tm][tn][r] + bias));
                }
        }
    }
    __syncthreads();

    // ---- layer 3: 256 -> 1, 4 threads per id, shuffle reduce
    {
        const int m = t >> 2, p = t & 3;
        float s = 0.f;
#pragma unroll
        for (int i = 0; i < 64; ++i) {
            const int k = p * 64 + i;
            const float a = __uint_as_float((unsigned int)buf[sw_off(m, k)] << 16);
            s += a * W3[k];
        }
        s += __shfl_xor(s, 1);
        s += __shfl_xor(s, 2);
        if (p == 0) out[id0 + m] = s + b3[0];
    }
}

// ---------------------------------------------------------------- launch
extern "C" void kernel_launch(void* const* d_in, const int* in_sizes, int n_in,
                              void* d_out, int out_size, void* d_ws, size_t ws_size,
                              hipStream_t stream) {
    const float* obs    = (const float*)d_in[0];
    const int*   edges  = (const int*)  d_in[1];
    const float* enc_W  = (const float*)d_in[2];
    const float* enc_b  = (const float*)d_in[3];
    const float* msg_W1 = (const float*)d_in[4];
    const float* msg_b1 = (const float*)d_in[5];
    const float* msg_W2 = (const float*)d_in[6];
    const float* msg_b2 = (const float*)d_in[7];
    const float* msg_W3 = (const float*)d_in[8];
    const float* msg_b3 = (const float*)d_in[9];
    const float* gru_Wi = (const float*)d_in[10];
    const float* gru_Wh = (const float*)d_in[11];
    const float* gru_bi = (const float*)d_in[12];
    const float* gru_bh = (const float*)d_in[13];
    const float* dec_W1 = (const float*)d_in[14];
    const float* dec_b1 = (const float*)d_in[15];
    const float* dec_W2 = (const float*)d_in[16];
    const float* dec_b2 = (const float*)d_in[17];
    const float* dec_W3 = (const float*)d_in[18];
    const float* dec_b3 = (const float*)d_in[19];

    float* x       = (float*)d_ws;                 // BN*128 f32
    float* aggr    = x + (size_t)BN * H;           // BN*128 f32
    float* inv_deg = aggr + (size_t)BN * H;        // BN f32
    unsigned short* wbf = (unsigned short*)(inv_deg + BN);   // 1540096 bf16
    unsigned short* P   = wbf + 1540096;           // BN*512 bf16 (75.5 MB)

    deg_kernel<<<(BGR + 255) / 256, 256, 0, stream>>>(edges, inv_deg);
    wt_kernel<<<1540096 / 256, 256, 0, stream>>>(msg_W1, msg_W2, msg_W3, gru_Wi, gru_Wh,
                                                 dec_W1, dec_W2, wbf);
    enc_kernel<<<BN * H / 256, 256, 0, stream>>>(obs, enc_W, enc_b, x);

    for (int s = 0; s < 4; ++s) {
        const unsigned short* W2T = wbf + 262144 + (size_t)s * 65536;
        const unsigned short* W3T = wbf + 524288 + (size_t)s * 32768;
        const unsigned short* WGs = wbf + 655360 + (size_t)s * 131072;
        const unsigned short* W1P = wbf + 1277952 + (size_t)s * 65536;
        proj_mfma<<<BN / 64, 512, 0, stream>>>(
            x, W1P, msg_b1 + (size_t)s * 256,
            W2T, msg_b2 + (size_t)s * 256, W3T, P, aggr);
        msg_mfma<<<NE / 64, 512, 0, stream>>>(
            P, edges,
            msg_b1 + (size_t)s * 256,
            W2T, msg_b2 + (size_t)s * 256,
            W3T,
            aggr);
        gru_mfma<<<BN / 64, 512, 0, stream>>>(
            x, aggr, inv_deg, WGs, msg_b3 + (size_t)s * 128,
            gru_bi + (size_t)s * 384, gru_bh + (size_t)s * 384);
    }

    dec_mfma<<<BGR * 8 / 64, 256, 0, stream>>>(
        x, wbf + 1179648, dec_b1, wbf + 1212416, dec_b2, dec_W3, dec_b3, (float*)d_out);
}

// Round 12
// 1470.782 us; speedup vs baseline: 1.0192x; 1.0192x over previous
//
#include <hip/hip_runtime.h>
#include <hip/hip_bf16.h>
#include <math.h>

#define BGR   8192        // graphs
#define NND   9           // nodes per graph
#define BN    73728       // BGR*NND
#define NE    131072      // BGR*16 explicit edges
#define H     128
#define MH    256
#define FIN   15

typedef __bf16 bf16_t;
typedef bf16_t bf16x8 __attribute__((ext_vector_type(8)));
typedef float  f32x4  __attribute__((ext_vector_type(4)));
typedef float  f32x16 __attribute__((ext_vector_type(16)));

__device__ __forceinline__ unsigned short f2bf(float f) {
    unsigned int u = __float_as_uint(f);
    u += 0x7fff + ((u >> 16) & 1);           // RNE (inputs are finite)
    return (unsigned short)(u >> 16);
}
__device__ __forceinline__ unsigned int pkbf(float a, float b) {
    union { __hip_bfloat162 h; unsigned int u; } un;
    un.h = __float22bfloat162_rn(make_float2(a, b));
    return un.u;
}
__device__ __forceinline__ bf16x8 as_frag(int4 v) {
    union { int4 i; bf16x8 f; } u; u.i = v; return u.f;
}
__device__ __forceinline__ float fast_tanh(float v) {
    float e = __expf(2.0f * v);
    return 1.0f - __fdividef(2.0f, e + 1.0f);
}
// 16-deep XOR swizzle, K=256 row (32x32 fragments, 2 lanes/bank = free)
__device__ __forceinline__ int sw16(int m, int k) {
    return m * 256 + ((((k >> 3) ^ (m & 15)) << 3) | (k & 7));
}
// 16-deep XOR swizzle, K=128 row (proj/x staging)
__device__ __forceinline__ int swp(int m, int k) {
    return m * 128 + ((((k >> 3) ^ (m & 15)) << 3) | (k & 7));
}
// legacy 8-deep swizzle (16x16 kernels: gru, dec)
__device__ __forceinline__ int sw_off(int m, int k) {
    return m * 256 + ((((k >> 3) ^ (m & 7)) << 3) | (k & 7));
}

// ---------------------------------------------------------------- deg kernel
__global__ void deg_kernel(const int* __restrict__ edges, float* __restrict__ inv_deg) {
    int g = blockIdx.x * 256 + threadIdx.x;
    if (g >= BGR) return;
    int cnt[NND];
#pragma unroll
    for (int n = 0; n < NND; ++n) cnt[n] = 1;   // self loop
    for (int j = 0; j < 16; ++j) {
        int d = edges[g * 32 + 16 + j];
#pragma unroll
        for (int n = 0; n < NND; ++n) cnt[n] += (d == n) ? 1 : 0;
    }
#pragma unroll
    for (int n = 0; n < NND; ++n) inv_deg[g * NND + n] = 1.0f / (float)cnt[n];
}

// ---------------------------------------------------------------- encoder
__global__ void enc_kernel(const float* __restrict__ obs, const float* __restrict__ W,
                           const float* __restrict__ b, float* __restrict__ x) {
    int tid = blockIdx.x * 256 + threadIdx.x;     // BN*128 threads
    int i = tid >> 7, h = tid & 127;
    float acc = b[h];
#pragma unroll
    for (int k = 0; k < FIN; ++k) acc += obs[i * FIN + k] * W[k * H + h];
    x[i * H + h] = tanhf(acc);
}

// ---------------------------------------------------------------- weight transpose+bf16
// out: [W1T 4x256x256(unused)][W2T 4x256x256][W3T 4x128x256][WG 4x512x256]
//      [dW1T 256x128][dW2T 256x256][W1P 4x512x128]
__global__ void wt_kernel(const float* __restrict__ W1, const float* __restrict__ W2,
                          const float* __restrict__ W3, const float* __restrict__ Wi,
                          const float* __restrict__ Wh, const float* __restrict__ dW1,
                          const float* __restrict__ dW2, unsigned short* __restrict__ out) {
    int idx = blockIdx.x * 256 + threadIdx.x;     // 1540096 total
    float v;
    if (idx < 262144) {
        int s = idx >> 16, r = idx & 65535, n = r >> 8, k = r & 255;
        v = W1[(s << 16) + (k << 8) + n];
    } else if (idx < 524288) {
        int i2 = idx - 262144;
        int s = i2 >> 16, r = i2 & 65535, n = r >> 8, k = r & 255;
        v = W2[(s << 16) + (k << 8) + n];
    } else if (idx < 655360) {
        int i3 = idx - 524288;
        int s = i3 >> 15, r = i3 & 32767, n = r >> 8, k = r & 255;
        v = W3[(s << 15) + (k << 7) + n];
    } else if (idx < 1179648) {
        int i4 = idx - 655360;                    // 0..524287
        int s = i4 >> 17, rr = i4 & 131071;
        int p = rr >> 8, k = rr & 255;
        int w = p >> 6, rem = p & 63;
        int gate = rem >> 4, c = rem & 15;
        int h = w * 16 + c;
        const int sb = s * 49152;                 // 128*384
        if (gate == 0)      v = (k < 128) ? Wi[sb + k * 384 + h]       : Wh[sb + (k - 128) * 384 + h];
        else if (gate == 1) v = (k < 128) ? Wi[sb + k * 384 + 128 + h] : Wh[sb + (k - 128) * 384 + 128 + h];
        else if (gate == 2) v = (k < 128) ? Wi[sb + k * 384 + 256 + h] : 0.f;
        else                v = (k < 128) ? 0.f                        : Wh[sb + (k - 128) * 384 + 256 + h];
    } else if (idx < 1212416) {
        int i5 = idx - 1179648;                   // dW1T [256][128]
        int n = i5 >> 7, k = i5 & 127;
        v = dW1[k * 256 + n];
    } else if (idx < 1277952) {
        int i6 = idx - 1212416;                   // dW2T [256][256]
        int n = i6 >> 8, k = i6 & 255;
        v = dW2[k * 256 + n];
    } else {
        int i7 = idx - 1277952;                   // W1P [s][p:512][k:128]
        int s = i7 >> 16, rr = i7 & 65535;
        int p = rr >> 7, k = rr & 127;
        int w = p >> 6, rem = p & 63;
        int side = rem >> 5, c = rem & 31;
        int n = w * 32 + c;
        v = W1[(s << 16) + ((k + side * 128) << 8) + n];
    }
    out[idx] = f2bf(v);
}

// ---------------------------------------------------------------- proj + self-message (step 0 only)
__global__ __launch_bounds__(512, 4) void proj_mfma(
        const float* __restrict__ x, const unsigned short* __restrict__ W1P,
        const float* __restrict__ b1,
        const unsigned short* __restrict__ W2T, const float* __restrict__ b2,
        const unsigned short* __restrict__ W3T,
        unsigned short* __restrict__ P, float* __restrict__ aggr) {
    __shared__ unsigned short lbuf[64 * 128];   // 16 KB
    __shared__ unsigned short abuf[64 * 256];   // 32 KB
    const int t = threadIdx.x;
    const int n0 = blockIdx.x * 64;             // node base
    const int wv = t >> 6, ln = t & 63, l31 = ln & 31, lh = ln >> 5;

    // stage bf16(x): 8 thr/row, 16 cols each
    {
        const int m = t >> 3, q = t & 7;
        const float* xs = x + (size_t)(n0 + m) * H + q * 16;
#pragma unroll
        for (int i = 0; i < 4; ++i) {
            float4 v = *(const float4*)(xs + i * 4);
            uint2 o; o.x = pkbf(v.x, v.y); o.y = pkbf(v.z, v.w);
            *(uint2*)(lbuf + swp(m, q * 16 + i * 4)) = o;
        }
    }
    __syncthreads();

    // ---- phase B: P-GEMM (u and v) + act1_self epilogue
    {
        f32x16 au[2], av[2];
#pragma unroll
        for (int a = 0; a < 2; ++a)
#pragma unroll
            for (int i = 0; i < 16; ++i) { au[a][i] = 0.f; av[a][i] = 0.f; }
        const unsigned short* wpu = W1P + (size_t)(wv * 64 + l31) * 128 + lh * 8;
        const unsigned short* wpv = W1P + (size_t)(wv * 64 + 32 + l31) * 128 + lh * 8;
#pragma unroll
        for (int ks = 0; ks < 8; ++ks) {
            const int kk = ks * 16 + lh * 8;
            bf16x8 a0 = as_frag(*(const int4*)(lbuf + swp(l31, kk)));
            bf16x8 a1 = as_frag(*(const int4*)(lbuf + swp(32 + l31, kk)));
            bf16x8 wu = as_frag(*(const int4*)(wpu + ks * 16));
            bf16x8 wvv = as_frag(*(const int4*)(wpv + ks * 16));
            au[0] = __builtin_amdgcn_mfma_f32_32x32x16_bf16(a0, wu, au[0], 0, 0, 0);
            au[1] = __builtin_amdgcn_mfma_f32_32x32x16_bf16(a1, wu, au[1], 0, 0, 0);
            av[0] = __builtin_amdgcn_mfma_f32_32x32x16_bf16(a0, wvv, av[0], 0, 0, 0);
            av[1] = __builtin_amdgcn_mfma_f32_32x32x16_bf16(a1, wvv, av[1], 0, 0, 0);
        }
        const int n = wv * 32 + l31;
        const float bias = b1[n];
#pragma unroll
        for (int mt = 0; mt < 2; ++mt)
#pragma unroll
            for (int reg = 0; reg < 16; ++reg) {
                const int mrow = mt * 32 + (reg & 3) + ((reg >> 2) << 3) + (lh << 2);
                const size_t node = n0 + mrow;
                P[node * 512 + n]       = f2bf(au[mt][reg]);
                P[node * 512 + 256 + n] = f2bf(av[mt][reg]);
                abuf[sw16(mrow, n)] = f2bf(fast_tanh(au[mt][reg] + av[mt][reg] + bias));
            }
    }
    __syncthreads();

    // ---- phase C: layer 2 (single-buffer abuf)
    {
        f32x16 acc0, acc1;
#pragma unroll
        for (int i = 0; i < 16; ++i) { acc0[i] = 0.f; acc1[i] = 0.f; }
        const unsigned short* wp = W2T + (size_t)(wv * 32 + l31) * 256 + lh * 8;
#pragma unroll
        for (int ks = 0; ks < 16; ++ks) {
            const int kk = ks * 16 + lh * 8;
            bf16x8 a0 = as_frag(*(const int4*)(abuf + sw16(l31, kk)));
            bf16x8 a1 = as_frag(*(const int4*)(abuf + sw16(32 + l31, kk)));
            bf16x8 bw = as_frag(*(const int4*)(wp + ks * 16));
            acc0 = __builtin_amdgcn_mfma_f32_32x32x16_bf16(a0, bw, acc0, 0, 0, 0);
            acc1 = __builtin_amdgcn_mfma_f32_32x32x16_bf16(a1, bw, acc1, 0, 0, 0);
        }
        __syncthreads();   // all reads of abuf done
        const int n = wv * 32 + l31;
        const float bias = b2[n];
#pragma unroll
        for (int reg = 0; reg < 16; ++reg) {
            const int mrow = (reg & 3) + ((reg >> 2) << 3) + (lh << 2);
            abuf[sw16(mrow, n)]      = f2bf(fast_tanh(acc0[reg] + bias));
            abuf[sw16(32 + mrow, n)] = f2bf(fast_tanh(acc1[reg] + bias));
        }
    }
    __syncthreads();

    // ---- phase D: layer 3 -> aggr plain store (self message, b3 deferred to GRU)
    {
        const int mt = wv & 1, nq = wv >> 1;
        const int n = nq * 32 + l31;
        f32x16 acc;
#pragma unroll
        for (int i = 0; i < 16; ++i) acc[i] = 0.f;
        const unsigned short* wp = W3T + (size_t)n * 256 + lh * 8;
#pragma unroll
        for (int ks = 0; ks < 16; ++ks) {
            const int kk = ks * 16 + lh * 8;
            bf16x8 a = as_frag(*(const int4*)(abuf + sw16(mt * 32 + l31, kk)));
            bf16x8 bw = as_frag(*(const int4*)(wp + ks * 16));
            acc = __builtin_amdgcn_mfma_f32_32x32x16_bf16(a, bw, acc, 0, 0, 0);
        }
#pragma unroll
        for (int reg = 0; reg < 16; ++reg) {
            const int m = mt * 32 + (reg & 3) + ((reg >> 2) << 3) + (lh << 2);
            aggr[(size_t)(n0 + m) * H + n] = acc[reg];
        }
    }
}

// ---------------------------------------------------------------- edge msg (layers 2-3), ZERO atomics
__global__ __launch_bounds__(512, 4) void msg_mfma(
        const unsigned short* __restrict__ P, const int* __restrict__ edges,
        const float* __restrict__ b1,
        const unsigned short* __restrict__ W2T, const float* __restrict__ b2,
        const unsigned short* __restrict__ W3T,
        float* __restrict__ aggr) {
    __shared__ unsigned short bufA[64 * 256];   // 32 KB: act1; later aggrL (f32 36x128 = 18 KB)
    __shared__ unsigned short bufB[64 * 256];   // 32 KB: act2
    __shared__ unsigned char sdstL[64];
    const int t  = threadIdx.x;
    const int e0 = blockIdx.x * 64;
    const int wv = t >> 6;
    const int ln = t & 63;
    const int l31 = ln & 31;
    const int lh  = ln >> 5;

    if (t < 64) {
        const int eg = e0 + t;
        sdstL[t] = (unsigned char)(((eg >> 4) & 3) * NND + edges[(eg >> 4) * 32 + 16 + (eg & 15)]);
    }
    {
        const int row = t >> 3;          // edge slot 0..63
        const int c0  = (t & 7) * 32;
        const int eg  = e0 + row;
        const int g = eg >> 4, j = eg & 15;
        const int sn = g * NND + edges[g * 32 + j];
        const int dn = g * NND + edges[g * 32 + 16 + j];
        const unsigned short* up = P + (size_t)dn * 512 + c0;
        const unsigned short* vp = P + (size_t)sn * 512 + 256 + c0;
#pragma unroll
        for (int i = 0; i < 4; ++i) {
            const uint4 uu = *(const uint4*)(up + i * 8);
            const uint4 vv = *(const uint4*)(vp + i * 8);
            const unsigned int ua[4] = {uu.x, uu.y, uu.z, uu.w};
            const unsigned int va[4] = {vv.x, vv.y, vv.z, vv.w};
            unsigned int op[4];
#pragma unroll
            for (int j2 = 0; j2 < 4; ++j2) {
                const float2 bb = *(const float2*)(b1 + c0 + i * 8 + j2 * 2);
                const float s0 = fast_tanh(__uint_as_float(ua[j2] << 16) +
                                           __uint_as_float(va[j2] << 16) + bb.x);
                const float s1 = fast_tanh(__uint_as_float(ua[j2] & 0xffff0000u) +
                                           __uint_as_float(va[j2] & 0xffff0000u) + bb.y);
                op[j2] = pkbf(s0, s1);
            }
            *(uint4*)(bufA + sw16(row, c0 + i * 8)) = make_uint4(op[0], op[1], op[2], op[3]);
        }
    }
    __syncthreads();

    // ---- layer 2
    {
        f32x16 acc0, acc1;
#pragma unroll
        for (int i = 0; i < 16; ++i) { acc0[i] = 0.f; acc1[i] = 0.f; }
        const unsigned short* wp = W2T + (size_t)(wv * 32 + l31) * 256 + lh * 8;
#pragma unroll
        for (int ks = 0; ks < 16; ++ks) {
            const int kk = ks * 16 + lh * 8;
            bf16x8 a0 = as_frag(*(const int4*)(bufA + sw16(l31, kk)));
            bf16x8 a1 = as_frag(*(const int4*)(bufA + sw16(32 + l31, kk)));
            bf16x8 bw = as_frag(*(const int4*)(wp + ks * 16));
            acc0 = __builtin_amdgcn_mfma_f32_32x32x16_bf16(a0, bw, acc0, 0, 0, 0);
            acc1 = __builtin_amdgcn_mfma_f32_32x32x16_bf16(a1, bw, acc1, 0, 0, 0);
        }
        const int n = wv * 32 + l31;
        const float bias = b2[n];
#pragma unroll
        for (int reg = 0; reg < 16; ++reg) {
            const int mrow = (reg & 3) + ((reg >> 2) << 3) + (lh << 2);
            bufB[sw16(mrow, n)]      = f2bf(fast_tanh(acc0[reg] + bias));
            bufB[sw16(32 + mrow, n)] = f2bf(fast_tanh(acc1[reg] + bias));
        }
    }
    __syncthreads();

    float* aL = (float*)bufA;
#pragma unroll
    for (int i = 0; i < 9; ++i) aL[i * 512 + t] = 0.f;
    __syncthreads();

    // ---- layer 3: LDS-atomic reduce into aggrL
    {
        const int mt = wv & 1, nq = wv >> 1;
        const int n = nq * 32 + l31;
        f32x16 acc;
#pragma unroll
        for (int i = 0; i < 16; ++i) acc[i] = 0.f;
        const unsigned short* wp = W3T + (size_t)n * 256 + lh * 8;
#pragma unroll
        for (int ks = 0; ks < 16; ++ks) {
            const int kk = ks * 16 + lh * 8;
            bf16x8 a = as_frag(*(const int4*)(bufB + sw16(mt * 32 + l31, kk)));
            bf16x8 bw = as_frag(*(const int4*)(wp + ks * 16));
            acc = __builtin_amdgcn_mfma_f32_32x32x16_bf16(a, bw, acc, 0, 0, 0);
        }
#pragma unroll
        for (int reg = 0; reg < 16; ++reg) {
            const int m = mt * 32 + (reg & 3) + ((reg >> 2) << 3) + (lh << 2);
            atomicAdd(&aL[(int)sdstL[m] * 128 + n], acc[reg]);
        }
    }
    __syncthreads();

    // ---- non-atomic RMW: this block exclusively owns its 36 nodes
    {
        float* gp = aggr + (size_t)blockIdx.x * 36 * 128;
#pragma unroll
        for (int i = 0; i < 9; ++i) {
            const int idx = i * 512 + t;
            gp[idx] += aL[idx];
        }
    }
}

// ---------------------------------------------------------------- GRU + next-step P/self-message
// Block owns nodes n0..n0+63 exclusively. After GRU: restage x_new (LDS bf16),
// P-GEMM for step s+1, act1_self, selfL2, selfL3 -> aggr plain store.
__global__ __launch_bounds__(512, 4) void grup_mfma(
        float* __restrict__ x, float* __restrict__ aggr, const float* __restrict__ inv_deg,
        const unsigned short* __restrict__ WG, const float* __restrict__ b3m,
        const float* __restrict__ bi, const float* __restrict__ bh,
        const unsigned short* __restrict__ W1Pn, const float* __restrict__ b1n,
        const unsigned short* __restrict__ W2Tn, const float* __restrict__ b2n,
        const unsigned short* __restrict__ W3Tn,
        unsigned short* __restrict__ P, int do_next) {
    __shared__ unsigned short bufA[64 * 256];   // 32 KB: gru staging, later abuf
    __shared__ unsigned short xbL[64 * 128];    // 16 KB: bf16 x_new
    const int t = threadIdx.x;
    const int n0 = blockIdx.x * 64;
    const int wv = t >> 6, ln = t & 63, lrow = ln & 15, lq = ln >> 4;
    const int l31 = ln & 31, lh = ln >> 5;

    // ---- gru staging: A = bf16([aggr*inv_deg + b3 | x])
    {
        const int m = t >> 3;
        const int q = t & 7;
        const int k0 = q * 32;
        const int node = n0 + m;
        if (q < 4) {
            const float scale = inv_deg[node];
            const float* src = aggr + (size_t)node * H + k0;
#pragma unroll
            for (int i = 0; i < 8; ++i) {
                float4 v = *(const float4*)(src + i * 4);
                const float4 bb = *(const float4*)(b3m + k0 + i * 4);
                v.x = v.x * scale + bb.x; v.y = v.y * scale + bb.y;
                v.z = v.z * scale + bb.z; v.w = v.w * scale + bb.w;
                uint2 o; o.x = pkbf(v.x, v.y); o.y = pkbf(v.z, v.w);
                *(uint2*)(bufA + sw_off(m, k0 + i * 4)) = o;
            }
        } else {
            const float* src = x + (size_t)node * H + (k0 - 128);
#pragma unroll
            for (int i = 0; i < 8; ++i) {
                float4 v = *(const float4*)(src + i * 4);
                uint2 o; o.x = pkbf(v.x, v.y); o.y = pkbf(v.z, v.w);
                *(uint2*)(bufA + sw_off(m, k0 + i * 4)) = o;
            }
        }
    }
    __syncthreads();

    {
        const f32x4 zero = {0.f, 0.f, 0.f, 0.f};
        f32x4 acc[4][4];    // [m-tile][gate]
#pragma unroll
        for (int i = 0; i < 4; ++i)
#pragma unroll
            for (int j = 0; j < 4; ++j) acc[i][j] = zero;

        const unsigned short* wgp = WG + (size_t)(wv * 64 + lrow) * 256;
#pragma unroll
        for (int kq = 0; kq < 8; ++kq) {
            const int ko = kq * 32 + lq * 8;
            bf16x8 af[4], bfr[4];
#pragma unroll
            for (int tm = 0; tm < 4; ++tm)
                af[tm] = as_frag(*(const int4*)(bufA + sw_off(tm * 16 + lrow, ko)));
#pragma unroll
            for (int g = 0; g < 4; ++g)
                bfr[g] = as_frag(*(const int4*)(wgp + (size_t)g * 16 * 256 + ko));
#pragma unroll
            for (int tm = 0; tm < 4; ++tm)
#pragma unroll
                for (int g = 0; g < 4; ++g)
                    acc[tm][g] = __builtin_amdgcn_mfma_f32_16x16x32_bf16(af[tm], bfr[g], acc[tm][g], 0, 0, 0);
        }

        // epilogue: gate mixing for h = wv*16 + lrow; write global x AND xbL
        const int h = wv * 16 + lrow;
        const float b_r = bi[h] + bh[h];
        const float b_z = bi[128 + h] + bh[128 + h];
        const float b_n = bi[256 + h];
        const float b_h = bh[256 + h];
#pragma unroll
        for (int tm = 0; tm < 4; ++tm) {
#pragma unroll
            for (int r = 0; r < 4; ++r) {
                const int ml = tm * 16 + lq * 4 + r;
                const int node = n0 + ml;
                const float irhr = acc[tm][0][r] + b_r;
                const float izhz = acc[tm][1][r] + b_z;
                const float inn  = acc[tm][2][r] + b_n;
                const float hn   = acc[tm][3][r] + b_h;
                const float rg = 1.f / (1.f + expf(-irhr));
                const float zg = 1.f / (1.f + expf(-izhz));
                const float ng = tanhf(inn + rg * hn);
                const float xo = x[(size_t)node * H + h];
                const float xn = (1.f - zg) * ng + zg * xo;
                x[(size_t)node * H + h] = xn;
                xbL[swp(ml, h)] = f2bf(xn);
            }
        }
    }
    if (!do_next) return;    // wave-uniform; all threads exit (no barrier after)
    __syncthreads();         // xbL complete; bufA free

    // ---- phase B: P-GEMM (u and v) from xbL + act1_self -> bufA (abuf)
    {
        f32x16 au[2], av[2];
#pragma unroll
        for (int a = 0; a < 2; ++a)
#pragma unroll
            for (int i = 0; i < 16; ++i) { au[a][i] = 0.f; av[a][i] = 0.f; }
        const unsigned short* wpu = W1Pn + (size_t)(wv * 64 + l31) * 128 + lh * 8;
        const unsigned short* wpv = W1Pn + (size_t)(wv * 64 + 32 + l31) * 128 + lh * 8;
#pragma unroll
        for (int ks = 0; ks < 8; ++ks) {
            const int kk = ks * 16 + lh * 8;
            bf16x8 a0 = as_frag(*(const int4*)(xbL + swp(l31, kk)));
            bf16x8 a1 = as_frag(*(const int4*)(xbL + swp(32 + l31, kk)));
            bf16x8 wu = as_frag(*(const int4*)(wpu + ks * 16));
            bf16x8 wvv = as_frag(*(const int4*)(wpv + ks * 16));
            au[0] = __builtin_amdgcn_mfma_f32_32x32x16_bf16(a0, wu, au[0], 0, 0, 0);
            au[1] = __builtin_amdgcn_mfma_f32_32x32x16_bf16(a1, wu, au[1], 0, 0, 0);
            av[0] = __builtin_amdgcn_mfma_f32_32x32x16_bf16(a0, wvv, av[0], 0, 0, 0);
            av[1] = __builtin_amdgcn_mfma_f32_32x32x16_bf16(a1, wvv, av[1], 0, 0, 0);
        }
        const int n = wv * 32 + l31;
        const float bias = b1n[n];
#pragma unroll
        for (int mt = 0; mt < 2; ++mt)
#pragma unroll
            for (int reg = 0; reg < 16; ++reg) {
                const int mrow = mt * 32 + (reg & 3) + ((reg >> 2) << 3) + (lh << 2);
                const size_t node = n0 + mrow;
                P[node * 512 + n]       = f2bf(au[mt][reg]);
                P[node * 512 + 256 + n] = f2bf(av[mt][reg]);
                bufA[sw16(mrow, n)] = f2bf(fast_tanh(au[mt][reg] + av[mt][reg] + bias));
            }
    }
    __syncthreads();

    // ---- phase C: self layer 2 (single-buffer bufA)
    {
        f32x16 acc0, acc1;
#pragma unroll
        for (int i = 0; i < 16; ++i) { acc0[i] = 0.f; acc1[i] = 0.f; }
        const unsigned short* wp = W2Tn + (size_t)(wv * 32 + l31) * 256 + lh * 8;
#pragma unroll
        for (int ks = 0; ks < 16; ++ks) {
            const int kk = ks * 16 + lh * 8;
            bf16x8 a0 = as_frag(*(const int4*)(bufA + sw16(l31, kk)));
            bf16x8 a1 = as_frag(*(const int4*)(bufA + sw16(32 + l31, kk)));
            bf16x8 bw = as_frag(*(const int4*)(wp + ks * 16));
            acc0 = __builtin_amdgcn_mfma_f32_32x32x16_bf16(a0, bw, acc0, 0, 0, 0);
            acc1 = __builtin_amdgcn_mfma_f32_32x32x16_bf16(a1, bw, acc1, 0, 0, 0);
        }
        __syncthreads();   // all reads of bufA done
        const int n = wv * 32 + l31;
        const float bias = b2n[n];
#pragma unroll
        for (int reg = 0; reg < 16; ++reg) {
            const int mrow = (reg & 3) + ((reg >> 2) << 3) + (lh << 2);
            bufA[sw16(mrow, n)]      = f2bf(fast_tanh(acc0[reg] + bias));
            bufA[sw16(32 + mrow, n)] = f2bf(fast_tanh(acc1[reg] + bias));
        }
    }
    __syncthreads();

    // ---- phase D: self layer 3 -> aggr plain store (base for step s+1)
    {
        const int mt = wv & 1, nq = wv >> 1;
        const int n = nq * 32 + l31;
        f32x16 acc;
#pragma unroll
        for (int i = 0; i < 16; ++i) acc[i] = 0.f;
        const unsigned short* wp = W3Tn + (size_t)n * 256 + lh * 8;
#pragma unroll
        for (int ks = 0; ks < 16; ++ks) {
            const int kk = ks * 16 + lh * 8;
            bf16x8 a = as_frag(*(const int4*)(bufA + sw16(mt * 32 + l31, kk)));
            bf16x8 bw = as_frag(*(const int4*)(wp + ks * 16));
            acc = __builtin_amdgcn_mfma_f32_32x32x16_bf16(a, bw, acc, 0, 0, 0);
        }
#pragma unroll
        for (int reg = 0; reg < 16; ++reg) {
            const int m = mt * 32 + (reg & 3) + ((reg >> 2) << 3) + (lh << 2);
            aggr[(size_t)(n0 + m) * H + n] = acc[reg];
        }
    }
}

// ---------------------------------------------------------------- decoder via MFMA (64 masked ids / block)
__global__ __launch_bounds__(256, 4) void dec_mfma(
        const float* __restrict__ x,
        const unsigned short* __restrict__ W1T, const float* __restrict__ b1,
        const unsigned short* __restrict__ W2T, const float* __restrict__ b2,
        const float* __restrict__ W3, const float* __restrict__ b3,
        float* __restrict__ out) {
    __shared__ unsigned short buf[64 * 256];   // 32 KB
    const int t = threadIdx.x;
    const int id0 = blockIdx.x * 64;
    const int wv = t >> 6, ln = t & 63, lrow = ln & 15, lq = ln >> 4;
    const int nbase = wv * 64;

    {
        const int m = t >> 2, q = t & 3;
        const int id = id0 + m;
        const int node = (id >> 3) * NND + (id & 7);
        const float* src = x + (size_t)node * H + q * 32;
#pragma unroll
        for (int i = 0; i < 8; ++i) {
            float4 v = *(const float4*)(src + i * 4);
            uint2 o; o.x = pkbf(v.x, v.y); o.y = pkbf(v.z, v.w);
            *(uint2*)(buf + sw_off(m, q * 32 + i * 4)) = o;
        }
    }
    __syncthreads();

    const f32x4 zero = {0.f, 0.f, 0.f, 0.f};

    // ---- layer 1: K=128 -> 256 cols
    {
        f32x4 acc[4][4];
#pragma unroll
        for (int i = 0; i < 4; ++i)
#pragma unroll
            for (int j = 0; j < 4; ++j) acc[i][j] = zero;
#pragma unroll
        for (int kq = 0; kq < 4; ++kq) {
            const int ko = kq * 32 + lq * 8;
            bf16x8 af[4], bfr[4];
#pragma unroll
            for (int tm = 0; tm < 4; ++tm)
                af[tm] = as_frag(*(const int4*)(buf + sw_off(tm * 16 + lrow, ko)));
#pragma unroll
            for (int tn = 0; tn < 4; ++tn)
                bfr[tn] = as_frag(*(const int4*)(W1T + (size_t)(nbase + tn * 16 + lrow) * 128 + ko));
#pragma unroll
            for (int tm = 0; tm < 4; ++tm)
#pragma unroll
                for (int tn = 0; tn < 4; ++tn)
                    acc[tm][tn] = __builtin_amdgcn_mfma_f32_16x16x32_bf16(af[tm], bfr[tn], acc[tm][tn], 0, 0, 0);
        }
        __syncthreads();
#pragma unroll
        for (int tn = 0; tn < 4; ++tn) {
            const int n = nbase + tn * 16 + lrow;
            const float bias = b1[n];
#pragma unroll
            for (int tm = 0; tm < 4; ++tm)
#pragma unroll
                for (int r = 0; r < 4; ++r) {
                    const int m = tm * 16 + lq * 4 + r;
                    buf[sw_off(m, n)] = f2bf(fast_tanh(acc[tm][tn][r] + bias));
                }
        }
    }
    __syncthreads();

    // ---- layer 2: K=256 -> 256 cols
    {
        f32x4 acc[4][4];
#pragma unroll
        for (int i = 0; i < 4; ++i)
#pragma unroll
            for (int j = 0; j < 4; ++j) acc[i][j] = zero;
#pragma unroll
        for (int kq = 0; kq < 8; ++kq) {
            const int ko = kq * 32 + lq * 8;
            bf16x8 af[4], bfr[4];
#pragma unroll
            for (int tm = 0; tm < 4; ++tm)
                af[tm] = as_frag(*(const int4*)(buf + sw_off(tm * 16 + lrow, ko)));
#pragma unroll
            for (int tn = 0; tn < 4; ++tn)
                bfr[tn] = as_frag(*(const int4*)(W2T + (size_t)(nbase + tn * 16 + lrow) * 256 + ko));
#pragma unroll
            for (int tm = 0; tm < 4; ++tm)
#pragma unroll
                for (int tn = 0; tn < 4; ++tn)
                    acc[tm][tn] = __builtin_amdgcn_mfma_f32_16x16x32_bf16(af[tm], bfr[tn], acc[tm][tn], 0, 0, 0);
        }
        __syncthreads();
#pragma unroll
        for (int tn = 0; tn < 4; ++tn) {
            const int n = nbase + tn * 16 + lrow;
            const float bias = b2[n];
#pragma unroll
            for (int tm = 0; tm < 4; ++tm)
#pragma unroll
                for (int r = 0; r < 4; ++r) {
                    const int m = tm * 16 + lq * 4 + r;
                    buf[sw_off(m, n)] = f2bf(fast_tanh(acc[tm][tn][r] + bias));
                }
        }
    }
    __syncthreads();

    // ---- layer 3: 256 -> 1, 4 threads per id, shuffle reduce
    {
        const int m = t >> 2, p = t & 3;
        float s = 0.f;
#pragma unroll
        for (int i = 0; i < 64; ++i) {
            const int k = p * 64 + i;
            const float a = __uint_as_float((unsigned int)buf[sw_off(m, k)] << 16);
            s += a * W3[k];
        }
        s += __shfl_xor(s, 1);
        s += __shfl_xor(s, 2);
        if (p == 0) out[id0 + m] = s + b3[0];
    }
}

// ---------------------------------------------------------------- launch
extern "C" void kernel_launch(void* const* d_in, const int* in_sizes, int n_in,
                              void* d_out, int out_size, void* d_ws, size_t ws_size,
                              hipStream_t stream) {
    const float* obs    = (const float*)d_in[0];
    const int*   edges  = (const int*)  d_in[1];
    const float* enc_W  = (const float*)d_in[2];
    const float* enc_b  = (const float*)d_in[3];
    const float* msg_W1 = (const float*)d_in[4];
    const float* msg_b1 = (const float*)d_in[5];
    const float* msg_W2 = (const float*)d_in[6];
    const float* msg_b2 = (const float*)d_in[7];
    const float* msg_W3 = (const float*)d_in[8];
    const float* msg_b3 = (const float*)d_in[9];
    const float* gru_Wi = (const float*)d_in[10];
    const float* gru_Wh = (const float*)d_in[11];
    const float* gru_bi = (const float*)d_in[12];
    const float* gru_bh = (const float*)d_in[13];
    const float* dec_W1 = (const float*)d_in[14];
    const float* dec_b1 = (const float*)d_in[15];
    const float* dec_W2 = (const float*)d_in[16];
    const float* dec_b2 = (const float*)d_in[17];
    const float* dec_W3 = (const float*)d_in[18];
    const float* dec_b3 = (const float*)d_in[19];

    float* x       = (float*)d_ws;                 // BN*128 f32
    float* aggr    = x + (size_t)BN * H;           // BN*128 f32
    float* inv_deg = aggr + (size_t)BN * H;        // BN f32
    unsigned short* wbf = (unsigned short*)(inv_deg + BN);   // 1540096 bf16
    unsigned short* P   = wbf + 1540096;           // BN*512 bf16 (75.5 MB)

    deg_kernel<<<(BGR + 255) / 256, 256, 0, stream>>>(edges, inv_deg);
    wt_kernel<<<1540096 / 256, 256, 0, stream>>>(msg_W1, msg_W2, msg_W3, gru_Wi, gru_Wh,
                                                 dec_W1, dec_W2, wbf);
    enc_kernel<<<BN * H / 256, 256, 0, stream>>>(obs, enc_W, enc_b, x);

    // step-0 P + self-message
    proj_mfma<<<BN / 64, 512, 0, stream>>>(
        x, wbf + 1277952, msg_b1,
        wbf + 262144, msg_b2, wbf + 524288, P, aggr);

    for (int s = 0; s < 4; ++s) {
        const unsigned short* W2T = wbf + 262144 + (size_t)s * 65536;
        const unsigned short* W3T = wbf + 524288 + (size_t)s * 32768;
        const unsigned short* WGs = wbf + 655360 + (size_t)s * 131072;
        const int nx = (s < 3) ? s + 1 : s;
        const unsigned short* W1Pn = wbf + 1277952 + (size_t)nx * 65536;
        const unsigned short* W2Tn = wbf + 262144 + (size_t)nx * 65536;
        const unsigned short* W3Tn = wbf + 524288 + (size_t)nx * 32768;
        msg_mfma<<<NE / 64, 512, 0, stream>>>(
            P, edges,
            msg_b1 + (size_t)s * 256,
            W2T, msg_b2 + (size_t)s * 256,
            W3T,
            aggr);
        grup_mfma<<<BN / 64, 512, 0, stream>>>(
            x, aggr, inv_deg, WGs, msg_b3 + (size_t)s * 128,
            gru_bi + (size_t)s * 384, gru_bh + (size_t)s * 384,
            W1Pn, msg_b1 + (size_t)nx * 256,
            W2Tn, msg_b2 + (size_t)nx * 256,
            W3Tn,
            P, (s < 3) ? 1 : 0);
    }

    dec_mfma<<<BGR * 8 / 64, 256, 0, stream>>>(
        x, wbf + 1179648, dec_b1, wbf + 1212416, dec_b2, dec_W3, dec_b3, (float*)d_out);
}

// Round 13
// 1450.317 us; speedup vs baseline: 1.0336x; 1.0141x over previous
//
#include <hip/hip_runtime.h>
#include <hip/hip_bf16.h>
#include <math.h>

#define BGR   8192        // graphs
#define NND   9           // nodes per graph
#define BN    73728       // BGR*NND
#define NE    131072      // BGR*16 explicit edges
#define H     128
#define MH    256
#define FIN   15

typedef __bf16 bf16_t;
typedef bf16_t bf16x8 __attribute__((ext_vector_type(8)));
typedef float  f32x4  __attribute__((ext_vector_type(4)));
typedef float  f32x16 __attribute__((ext_vector_type(16)));

__device__ __forceinline__ unsigned short f2bf(float f) {
    unsigned int u = __float_as_uint(f);
    u += 0x7fff + ((u >> 16) & 1);           // RNE (inputs are finite)
    return (unsigned short)(u >> 16);
}
__device__ __forceinline__ unsigned int pkbf(float a, float b) {
    union { __hip_bfloat162 h; unsigned int u; } un;
    un.h = __float22bfloat162_rn(make_float2(a, b));
    return un.u;
}
__device__ __forceinline__ bf16x8 as_frag(int4 v) {
    union { int4 i; bf16x8 f; } u; u.i = v; return u.f;
}
__device__ __forceinline__ float fast_tanh(float v) {
    float e = __expf(2.0f * v);
    return 1.0f - __fdividef(2.0f, e + 1.0f);
}
// 16-deep XOR swizzle, K=256 row (32x32 fragments, 2 lanes/bank = free)
__device__ __forceinline__ int sw16(int m, int k) {
    return m * 256 + ((((k >> 3) ^ (m & 15)) << 3) | (k & 7));
}
// 16-deep XOR swizzle, K=128 row (proj/x staging)
__device__ __forceinline__ int swp(int m, int k) {
    return m * 128 + ((((k >> 3) ^ (m & 15)) << 3) | (k & 7));
}
// legacy 8-deep swizzle (16x16 kernels: gru, dec)
__device__ __forceinline__ int sw_off(int m, int k) {
    return m * 256 + ((((k >> 3) ^ (m & 7)) << 3) | (k & 7));
}

// ---------------------------------------------------------------- deg kernel
__global__ void deg_kernel(const int* __restrict__ edges, float* __restrict__ inv_deg) {
    int g = blockIdx.x * 256 + threadIdx.x;
    if (g >= BGR) return;
    int cnt[NND];
#pragma unroll
    for (int n = 0; n < NND; ++n) cnt[n] = 1;   // self loop
    for (int j = 0; j < 16; ++j) {
        int d = edges[g * 32 + 16 + j];
#pragma unroll
        for (int n = 0; n < NND; ++n) cnt[n] += (d == n) ? 1 : 0;
    }
#pragma unroll
    for (int n = 0; n < NND; ++n) inv_deg[g * NND + n] = 1.0f / (float)cnt[n];
}

// ---------------------------------------------------------------- encoder
__global__ void enc_kernel(const float* __restrict__ obs, const float* __restrict__ W,
                           const float* __restrict__ b, float* __restrict__ x) {
    int tid = blockIdx.x * 256 + threadIdx.x;     // BN*128 threads
    int i = tid >> 7, h = tid & 127;
    float acc = b[h];
#pragma unroll
    for (int k = 0; k < FIN; ++k) acc += obs[i * FIN + k] * W[k * H + h];
    x[i * H + h] = tanhf(acc);
}

// ---------------------------------------------------------------- weight transpose+bf16
// out: [W1T 4x256x256(unused)][W2T 4x256x256][W3T 4x128x256][WG 4x512x256]
//      [dW1T 256x128][dW2T 256x256][W1P 4x512x128]
__global__ void wt_kernel(const float* __restrict__ W1, const float* __restrict__ W2,
                          const float* __restrict__ W3, const float* __restrict__ Wi,
                          const float* __restrict__ Wh, const float* __restrict__ dW1,
                          const float* __restrict__ dW2, unsigned short* __restrict__ out) {
    int idx = blockIdx.x * 256 + threadIdx.x;     // 1540096 total
    float v;
    if (idx < 262144) {
        int s = idx >> 16, r = idx & 65535, n = r >> 8, k = r & 255;
        v = W1[(s << 16) + (k << 8) + n];
    } else if (idx < 524288) {
        int i2 = idx - 262144;
        int s = i2 >> 16, r = i2 & 65535, n = r >> 8, k = r & 255;
        v = W2[(s << 16) + (k << 8) + n];
    } else if (idx < 655360) {
        int i3 = idx - 524288;
        int s = i3 >> 15, r = i3 & 32767, n = r >> 8, k = r & 255;
        v = W3[(s << 15) + (k << 7) + n];
    } else if (idx < 1179648) {
        int i4 = idx - 655360;                    // 0..524287
        int s = i4 >> 17, rr = i4 & 131071;
        int p = rr >> 8, k = rr & 255;
        int w = p >> 6, rem = p & 63;
        int gate = rem >> 4, c = rem & 15;
        int h = w * 16 + c;
        const int sb = s * 49152;                 // 128*384
        if (gate == 0)      v = (k < 128) ? Wi[sb + k * 384 + h]       : Wh[sb + (k - 128) * 384 + h];
        else if (gate == 1) v = (k < 128) ? Wi[sb + k * 384 + 128 + h] : Wh[sb + (k - 128) * 384 + 128 + h];
        else if (gate == 2) v = (k < 128) ? Wi[sb + k * 384 + 256 + h] : 0.f;
        else                v = (k < 128) ? 0.f                        : Wh[sb + (k - 128) * 384 + 256 + h];
    } else if (idx < 1212416) {
        int i5 = idx - 1179648;                   // dW1T [256][128]
        int n = i5 >> 7, k = i5 & 127;
        v = dW1[k * 256 + n];
    } else if (idx < 1277952) {
        int i6 = idx - 1212416;                   // dW2T [256][256]
        int n = i6 >> 8, k = i6 & 255;
        v = dW2[k * 256 + n];
    } else {
        int i7 = idx - 1277952;                   // W1P [s][p:512][k:128]
        int s = i7 >> 16, rr = i7 & 65535;
        int p = rr >> 7, k = rr & 127;
        int w = p >> 6, rem = p & 63;
        int side = rem >> 5, c = rem & 31;
        int n = w * 32 + c;
        v = W1[(s << 16) + ((k + side * 128) << 8) + n];
    }
    out[idx] = f2bf(v);
}

// ---------------------------------------------------------------- proj + self-message (step 0 only)
__global__ __launch_bounds__(512, 4) void proj_mfma(
        const float* __restrict__ x, const unsigned short* __restrict__ W1P,
        const float* __restrict__ b1,
        const unsigned short* __restrict__ W2T, const float* __restrict__ b2,
        const unsigned short* __restrict__ W3T,
        unsigned short* __restrict__ P, float* __restrict__ aggr) {
    __shared__ unsigned short lbuf[64 * 128];   // 16 KB
    __shared__ unsigned short abuf[64 * 256];   // 32 KB
    const int t = threadIdx.x;
    const int n0 = blockIdx.x * 64;             // node base
    const int wv = t >> 6, ln = t & 63, l31 = ln & 31, lh = ln >> 5;

    // stage bf16(x): 8 thr/row, 16 cols each
    {
        const int m = t >> 3, q = t & 7;
        const float* xs = x + (size_t)(n0 + m) * H + q * 16;
#pragma unroll
        for (int i = 0; i < 4; ++i) {
            float4 v = *(const float4*)(xs + i * 4);
            uint2 o; o.x = pkbf(v.x, v.y); o.y = pkbf(v.z, v.w);
            *(uint2*)(lbuf + swp(m, q * 16 + i * 4)) = o;
        }
    }
    __syncthreads();

    // ---- phase B: P-GEMM (u and v) + act1_self epilogue
    {
        f32x16 au[2], av[2];
#pragma unroll
        for (int a = 0; a < 2; ++a)
#pragma unroll
            for (int i = 0; i < 16; ++i) { au[a][i] = 0.f; av[a][i] = 0.f; }
        const unsigned short* wpu = W1P + (size_t)(wv * 64 + l31) * 128 + lh * 8;
        const unsigned short* wpv = W1P + (size_t)(wv * 64 + 32 + l31) * 128 + lh * 8;
#pragma unroll
        for (int ks = 0; ks < 8; ++ks) {
            const int kk = ks * 16 + lh * 8;
            bf16x8 a0 = as_frag(*(const int4*)(lbuf + swp(l31, kk)));
            bf16x8 a1 = as_frag(*(const int4*)(lbuf + swp(32 + l31, kk)));
            bf16x8 wu = as_frag(*(const int4*)(wpu + ks * 16));
            bf16x8 wvv = as_frag(*(const int4*)(wpv + ks * 16));
            au[0] = __builtin_amdgcn_mfma_f32_32x32x16_bf16(a0, wu, au[0], 0, 0, 0);
            au[1] = __builtin_amdgcn_mfma_f32_32x32x16_bf16(a1, wu, au[1], 0, 0, 0);
            av[0] = __builtin_amdgcn_mfma_f32_32x32x16_bf16(a0, wvv, av[0], 0, 0, 0);
            av[1] = __builtin_amdgcn_mfma_f32_32x32x16_bf16(a1, wvv, av[1], 0, 0, 0);
        }
        const int n = wv * 32 + l31;
        const float bias = b1[n];
#pragma unroll
        for (int mt = 0; mt < 2; ++mt)
#pragma unroll
            for (int reg = 0; reg < 16; ++reg) {
                const int mrow = mt * 32 + (reg & 3) + ((reg >> 2) << 3) + (lh << 2);
                const size_t node = n0 + mrow;
                P[node * 512 + n]       = f2bf(au[mt][reg]);
                P[node * 512 + 256 + n] = f2bf(av[mt][reg]);
                abuf[sw16(mrow, n)] = f2bf(fast_tanh(au[mt][reg] + av[mt][reg] + bias));
            }
    }
    __syncthreads();

    // ---- phase C: layer 2 (single-buffer abuf)
    {
        f32x16 acc0, acc1;
#pragma unroll
        for (int i = 0; i < 16; ++i) { acc0[i] = 0.f; acc1[i] = 0.f; }
        const unsigned short* wp = W2T + (size_t)(wv * 32 + l31) * 256 + lh * 8;
#pragma unroll
        for (int ks = 0; ks < 16; ++ks) {
            const int kk = ks * 16 + lh * 8;
            bf16x8 a0 = as_frag(*(const int4*)(abuf + sw16(l31, kk)));
            bf16x8 a1 = as_frag(*(const int4*)(abuf + sw16(32 + l31, kk)));
            bf16x8 bw = as_frag(*(const int4*)(wp + ks * 16));
            acc0 = __builtin_amdgcn_mfma_f32_32x32x16_bf16(a0, bw, acc0, 0, 0, 0);
            acc1 = __builtin_amdgcn_mfma_f32_32x32x16_bf16(a1, bw, acc1, 0, 0, 0);
        }
        __syncthreads();   // all reads of abuf done
        const int n = wv * 32 + l31;
        const float bias = b2[n];
#pragma unroll
        for (int reg = 0; reg < 16; ++reg) {
            const int mrow = (reg & 3) + ((reg >> 2) << 3) + (lh << 2);
            abuf[sw16(mrow, n)]      = f2bf(fast_tanh(acc0[reg] + bias));
            abuf[sw16(32 + mrow, n)] = f2bf(fast_tanh(acc1[reg] + bias));
        }
    }
    __syncthreads();

    // ---- phase D: layer 3 -> aggr plain store (self message, b3 deferred to GRU)
    {
        const int mt = wv & 1, nq = wv >> 1;
        const int n = nq * 32 + l31;
        f32x16 acc;
#pragma unroll
        for (int i = 0; i < 16; ++i) acc[i] = 0.f;
        const unsigned short* wp = W3T + (size_t)n * 256 + lh * 8;
#pragma unroll
        for (int ks = 0; ks < 16; ++ks) {
            const int kk = ks * 16 + lh * 8;
            bf16x8 a = as_frag(*(const int4*)(abuf + sw16(mt * 32 + l31, kk)));
            bf16x8 bw = as_frag(*(const int4*)(wp + ks * 16));
            acc = __builtin_amdgcn_mfma_f32_32x32x16_bf16(a, bw, acc, 0, 0, 0);
        }
#pragma unroll
        for (int reg = 0; reg < 16; ++reg) {
            const int m = mt * 32 + (reg & 3) + ((reg >> 2) << 3) + (lh << 2);
            aggr[(size_t)(n0 + m) * H + n] = acc[reg];
        }
    }
}

// ---------------------------------------------------------------- edge msg (layers 2-3), ZERO atomics
// SINGLE 32 KB act buffer + separate 18 KB aggrL -> ~51 KB LDS -> 3 blocks/CU at
// __launch_bounds__(512,6) (reg cap 85 >= measured 52). One extra barrier splits
// the L2 phase (read-all -> sync -> write-in-place).
__global__ __launch_bounds__(512, 6) void msg_mfma(
        const unsigned short* __restrict__ P, const int* __restrict__ edges,
        const float* __restrict__ b1,
        const unsigned short* __restrict__ W2T, const float* __restrict__ b2,
        const unsigned short* __restrict__ W3T,
        float* __restrict__ aggr) {
    __shared__ unsigned short buf[64 * 256];    // 32 KB: act1, then act2
    __shared__ float aggrL[36 * 128];           // 18 KB: block-local aggregate
    __shared__ unsigned char sdstL[64];
    const int t  = threadIdx.x;
    const int e0 = blockIdx.x * 64;
    const int wv = t >> 6;
    const int ln = t & 63;
    const int l31 = ln & 31;
    const int lh  = ln >> 5;

    if (t < 64) {
        const int eg = e0 + t;
        sdstL[t] = (unsigned char)(((eg >> 4) & 3) * NND + edges[(eg >> 4) * 32 + 16 + (eg & 15)]);
    }
    // zero aggrL (untouched until the L3 reduce)
#pragma unroll
    for (int i = 0; i < 9; ++i) aggrL[i * 512 + t] = 0.f;

    // ---- stage act1 = tanh(u_dst + v_src + b1)
    {
        const int row = t >> 3;          // edge slot 0..63
        const int c0  = (t & 7) * 32;
        const int eg  = e0 + row;
        const int g = eg >> 4, j = eg & 15;
        const int sn = g * NND + edges[g * 32 + j];
        const int dn = g * NND + edges[g * 32 + 16 + j];
        const unsigned short* up = P + (size_t)dn * 512 + c0;
        const unsigned short* vp = P + (size_t)sn * 512 + 256 + c0;
#pragma unroll
        for (int i = 0; i < 4; ++i) {
            const uint4 uu = *(const uint4*)(up + i * 8);
            const uint4 vv = *(const uint4*)(vp + i * 8);
            const unsigned int ua[4] = {uu.x, uu.y, uu.z, uu.w};
            const unsigned int va[4] = {vv.x, vv.y, vv.z, vv.w};
            unsigned int op[4];
#pragma unroll
            for (int j2 = 0; j2 < 4; ++j2) {
                const float2 bb = *(const float2*)(b1 + c0 + i * 8 + j2 * 2);
                const float s0 = fast_tanh(__uint_as_float(ua[j2] << 16) +
                                           __uint_as_float(va[j2] << 16) + bb.x);
                const float s1 = fast_tanh(__uint_as_float(ua[j2] & 0xffff0000u) +
                                           __uint_as_float(va[j2] & 0xffff0000u) + bb.y);
                op[j2] = pkbf(s0, s1);
            }
            *(uint4*)(buf + sw16(row, c0 + i * 8)) = make_uint4(op[0], op[1], op[2], op[3]);
        }
    }
    __syncthreads();   // b1: act1 + sdstL + zeros visible

    // ---- layer 2: read buf into regs, sync, write act2 in place
    {
        f32x16 acc0, acc1;
#pragma unroll
        for (int i = 0; i < 16; ++i) { acc0[i] = 0.f; acc1[i] = 0.f; }
        const unsigned short* wp = W2T + (size_t)(wv * 32 + l31) * 256 + lh * 8;
#pragma unroll
        for (int ks = 0; ks < 16; ++ks) {
            const int kk = ks * 16 + lh * 8;
            bf16x8 a0 = as_frag(*(const int4*)(buf + sw16(l31, kk)));
            bf16x8 a1 = as_frag(*(const int4*)(buf + sw16(32 + l31, kk)));
            bf16x8 bw = as_frag(*(const int4*)(wp + ks * 16));
            acc0 = __builtin_amdgcn_mfma_f32_32x32x16_bf16(a0, bw, acc0, 0, 0, 0);
            acc1 = __builtin_amdgcn_mfma_f32_32x32x16_bf16(a1, bw, acc1, 0, 0, 0);
        }
        __syncthreads();   // b2: all reads of act1 done
        const int n = wv * 32 + l31;
        const float bias = b2[n];
#pragma unroll
        for (int reg = 0; reg < 16; ++reg) {
            const int mrow = (reg & 3) + ((reg >> 2) << 3) + (lh << 2);
            buf[sw16(mrow, n)]      = f2bf(fast_tanh(acc0[reg] + bias));
            buf[sw16(32 + mrow, n)] = f2bf(fast_tanh(acc1[reg] + bias));
        }
    }
    __syncthreads();   // b3: act2 visible

    // ---- layer 3: read buf (act2), LDS-atomic reduce into aggrL
    {
        const int mt = wv & 1, nq = wv >> 1;
        const int n = nq * 32 + l31;
        f32x16 acc;
#pragma unroll
        for (int i = 0; i < 16; ++i) acc[i] = 0.f;
        const unsigned short* wp = W3T + (size_t)n * 256 + lh * 8;
#pragma unroll
        for (int ks = 0; ks < 16; ++ks) {
            const int kk = ks * 16 + lh * 8;
            bf16x8 a = as_frag(*(const int4*)(buf + sw16(mt * 32 + l31, kk)));
            bf16x8 bw = as_frag(*(const int4*)(wp + ks * 16));
            acc = __builtin_amdgcn_mfma_f32_32x32x16_bf16(a, bw, acc, 0, 0, 0);
        }
#pragma unroll
        for (int reg = 0; reg < 16; ++reg) {
            const int m = mt * 32 + (reg & 3) + ((reg >> 2) << 3) + (lh << 2);
            atomicAdd(&aggrL[(int)sdstL[m] * 128 + n], acc[reg]);
        }
    }
    __syncthreads();   // b4: reduction complete

    // ---- non-atomic RMW: this block exclusively owns its 36 nodes
    {
        float* gp = aggr + (size_t)blockIdx.x * 36 * 128;
#pragma unroll
        for (int i = 0; i < 9; ++i) {
            const int idx = i * 512 + t;
            gp[idx] += aggrL[idx];
        }
    }
}

// ---------------------------------------------------------------- GRU + next-step P/self-message
__global__ __launch_bounds__(512, 4) void grup_mfma(
        float* __restrict__ x, float* __restrict__ aggr, const float* __restrict__ inv_deg,
        const unsigned short* __restrict__ WG, const float* __restrict__ b3m,
        const float* __restrict__ bi, const float* __restrict__ bh,
        const unsigned short* __restrict__ W1Pn, const float* __restrict__ b1n,
        const unsigned short* __restrict__ W2Tn, const float* __restrict__ b2n,
        const unsigned short* __restrict__ W3Tn,
        unsigned short* __restrict__ P, int do_next) {
    __shared__ unsigned short bufA[64 * 256];   // 32 KB: gru staging, later abuf
    __shared__ unsigned short xbL[64 * 128];    // 16 KB: bf16 x_new
    const int t = threadIdx.x;
    const int n0 = blockIdx.x * 64;
    const int wv = t >> 6, ln = t & 63, lrow = ln & 15, lq = ln >> 4;
    const int l31 = ln & 31, lh = ln >> 5;

    // ---- gru staging: A = bf16([aggr*inv_deg + b3 | x])
    {
        const int m = t >> 3;
        const int q = t & 7;
        const int k0 = q * 32;
        const int node = n0 + m;
        if (q < 4) {
            const float scale = inv_deg[node];
            const float* src = aggr + (size_t)node * H + k0;
#pragma unroll
            for (int i = 0; i < 8; ++i) {
                float4 v = *(const float4*)(src + i * 4);
                const float4 bb = *(const float4*)(b3m + k0 + i * 4);
                v.x = v.x * scale + bb.x; v.y = v.y * scale + bb.y;
                v.z = v.z * scale + bb.z; v.w = v.w * scale + bb.w;
                uint2 o; o.x = pkbf(v.x, v.y); o.y = pkbf(v.z, v.w);
                *(uint2*)(bufA + sw_off(m, k0 + i * 4)) = o;
            }
        } else {
            const float* src = x + (size_t)node * H + (k0 - 128);
#pragma unroll
            for (int i = 0; i < 8; ++i) {
                float4 v = *(const float4*)(src + i * 4);
                uint2 o; o.x = pkbf(v.x, v.y); o.y = pkbf(v.z, v.w);
                *(uint2*)(bufA + sw_off(m, k0 + i * 4)) = o;
            }
        }
    }
    __syncthreads();

    {
        const f32x4 zero = {0.f, 0.f, 0.f, 0.f};
        f32x4 acc[4][4];    // [m-tile][gate]
#pragma unroll
        for (int i = 0; i < 4; ++i)
#pragma unroll
            for (int j = 0; j < 4; ++j) acc[i][j] = zero;

        const unsigned short* wgp = WG + (size_t)(wv * 64 + lrow) * 256;
#pragma unroll
        for (int kq = 0; kq < 8; ++kq) {
            const int ko = kq * 32 + lq * 8;
            bf16x8 af[4], bfr[4];
#pragma unroll
            for (int tm = 0; tm < 4; ++tm)
                af[tm] = as_frag(*(const int4*)(bufA + sw_off(tm * 16 + lrow, ko)));
#pragma unroll
            for (int g = 0; g < 4; ++g)
                bfr[g] = as_frag(*(const int4*)(wgp + (size_t)g * 16 * 256 + ko));
#pragma unroll
            for (int tm = 0; tm < 4; ++tm)
#pragma unroll
                for (int g = 0; g < 4; ++g)
                    acc[tm][g] = __builtin_amdgcn_mfma_f32_16x16x32_bf16(af[tm], bfr[g], acc[tm][g], 0, 0, 0);
        }

        // epilogue: gate mixing for h = wv*16 + lrow; write global x AND xbL
        const int h = wv * 16 + lrow;
        const float b_r = bi[h] + bh[h];
        const float b_z = bi[128 + h] + bh[128 + h];
        const float b_n = bi[256 + h];
        const float b_h = bh[256 + h];
#pragma unroll
        for (int tm = 0; tm < 4; ++tm) {
#pragma unroll
            for (int r = 0; r < 4; ++r) {
                const int ml = tm * 16 + lq * 4 + r;
                const int node = n0 + ml;
                const float irhr = acc[tm][0][r] + b_r;
                const float izhz = acc[tm][1][r] + b_z;
                const float inn  = acc[tm][2][r] + b_n;
                const float hn   = acc[tm][3][r] + b_h;
                const float rg = 1.f / (1.f + expf(-irhr));
                const float zg = 1.f / (1.f + expf(-izhz));
                const float ng = tanhf(inn + rg * hn);
                const float xo = x[(size_t)node * H + h];
                const float xn = (1.f - zg) * ng + zg * xo;
                x[(size_t)node * H + h] = xn;
                xbL[swp(ml, h)] = f2bf(xn);
            }
        }
    }
    if (!do_next) return;    // wave-uniform; all threads exit (no barrier after)
    __syncthreads();         // xbL complete; bufA free

    // ---- phase B: P-GEMM (u and v) from xbL + act1_self -> bufA (abuf)
    {
        f32x16 au[2], av[2];
#pragma unroll
        for (int a = 0; a < 2; ++a)
#pragma unroll
            for (int i = 0; i < 16; ++i) { au[a][i] = 0.f; av[a][i] = 0.f; }
        const unsigned short* wpu = W1Pn + (size_t)(wv * 64 + l31) * 128 + lh * 8;
        const unsigned short* wpv = W1Pn + (size_t)(wv * 64 + 32 + l31) * 128 + lh * 8;
#pragma unroll
        for (int ks = 0; ks < 8; ++ks) {
            const int kk = ks * 16 + lh * 8;
            bf16x8 a0 = as_frag(*(const int4*)(xbL + swp(l31, kk)));
            bf16x8 a1 = as_frag(*(const int4*)(xbL + swp(32 + l31, kk)));
            bf16x8 wu = as_frag(*(const int4*)(wpu + ks * 16));
            bf16x8 wvv = as_frag(*(const int4*)(wpv + ks * 16));
            au[0] = __builtin_amdgcn_mfma_f32_32x32x16_bf16(a0, wu, au[0], 0, 0, 0);
            au[1] = __builtin_amdgcn_mfma_f32_32x32x16_bf16(a1, wu, au[1], 0, 0, 0);
            av[0] = __builtin_amdgcn_mfma_f32_32x32x16_bf16(a0, wvv, av[0], 0, 0, 0);
            av[1] = __builtin_amdgcn_mfma_f32_32x32x16_bf16(a1, wvv, av[1], 0, 0, 0);
        }
        const int n = wv * 32 + l31;
        const float bias = b1n[n];
#pragma unroll
        for (int mt = 0; mt < 2; ++mt)
#pragma unroll
            for (int reg = 0; reg < 16; ++reg) {
                const int mrow = mt * 32 + (reg & 3) + ((reg >> 2) << 3) + (lh << 2);
                const size_t node = n0 + mrow;
                P[node * 512 + n]       = f2bf(au[mt][reg]);
                P[node * 512 + 256 + n] = f2bf(av[mt][reg]);
                bufA[sw16(mrow, n)] = f2bf(fast_tanh(au[mt][reg] + av[mt][reg] + bias));
            }
    }
    __syncthreads();

    // ---- phase C: self layer 2 (single-buffer bufA)
    {
        f32x16 acc0, acc1;
#pragma unroll
        for (int i = 0; i < 16; ++i) { acc0[i] = 0.f; acc1[i] = 0.f; }
        const unsigned short* wp = W2Tn + (size_t)(wv * 32 + l31) * 256 + lh * 8;
#pragma unroll
        for (int ks = 0; ks < 16; ++ks) {
            const int kk = ks * 16 + lh * 8;
            bf16x8 a0 = as_frag(*(const int4*)(bufA + sw16(l31, kk)));
            bf16x8 a1 = as_frag(*(const int4*)(bufA + sw16(32 + l31, kk)));
            bf16x8 bw = as_frag(*(const int4*)(wp + ks * 16));
            acc0 = __builtin_amdgcn_mfma_f32_32x32x16_bf16(a0, bw, acc0, 0, 0, 0);
            acc1 = __builtin_amdgcn_mfma_f32_32x32x16_bf16(a1, bw, acc1, 0, 0, 0);
        }
        __syncthreads();   // all reads of bufA done
        const int n = wv * 32 + l31;
        const float bias = b2n[n];
#pragma unroll
        for (int reg = 0; reg < 16; ++reg) {
            const int mrow = (reg & 3) + ((reg >> 2) << 3) + (lh << 2);
            bufA[sw16(mrow, n)]      = f2bf(fast_tanh(acc0[reg] + bias));
            bufA[sw16(32 + mrow, n)] = f2bf(fast_tanh(acc1[reg] + bias));
        }
    }
    __syncthreads();

    // ---- phase D: self layer 3 -> aggr plain store (base for step s+1)
    {
        const int mt = wv & 1, nq = wv >> 1;
        const int n = nq * 32 + l31;
        f32x16 acc;
#pragma unroll
        for (int i = 0; i < 16; ++i) acc[i] = 0.f;
        const unsigned short* wp = W3Tn + (size_t)n * 256 + lh * 8;
#pragma unroll
        for (int ks = 0; ks < 16; ++ks) {
            const int kk = ks * 16 + lh * 8;
            bf16x8 a = as_frag(*(const int4*)(bufA + sw16(mt * 32 + l31, kk)));
            bf16x8 bw = as_frag(*(const int4*)(wp + ks * 16));
            acc = __builtin_amdgcn_mfma_f32_32x32x16_bf16(a, bw, acc, 0, 0, 0);
        }
#pragma unroll
        for (int reg = 0; reg < 16; ++reg) {
            const int m = mt * 32 + (reg & 3) + ((reg >> 2) << 3) + (lh << 2);
            aggr[(size_t)(n0 + m) * H + n] = acc[reg];
        }
    }
}

// ---------------------------------------------------------------- decoder via MFMA (64 masked ids / block)
__global__ __launch_bounds__(256, 4) void dec_mfma(
        const float* __restrict__ x,
        const unsigned short* __restrict__ W1T, const float* __restrict__ b1,
        const unsigned short* __restrict__ W2T, const float* __restrict__ b2,
        const float* __restrict__ W3, const float* __restrict__ b3,
        float* __restrict__ out) {
    __shared__ unsigned short buf[64 * 256];   // 32 KB
    const int t = threadIdx.x;
    const int id0 = blockIdx.x * 64;
    const int wv = t >> 6, ln = t & 63, lrow = ln & 15, lq = ln >> 4;
    const int nbase = wv * 64;

    {
        const int m = t >> 2, q = t & 3;
        const int id = id0 + m;
        const int node = (id >> 3) * NND + (id & 7);
        const float* src = x + (size_t)node * H + q * 32;
#pragma unroll
        for (int i = 0; i < 8; ++i) {
            float4 v = *(const float4*)(src + i * 4);
            uint2 o; o.x = pkbf(v.x, v.y); o.y = pkbf(v.z, v.w);
            *(uint2*)(buf + sw_off(m, q * 32 + i * 4)) = o;
        }
    }
    __syncthreads();

    const f32x4 zero = {0.f, 0.f, 0.f, 0.f};

    // ---- layer 1: K=128 -> 256 cols
    {
        f32x4 acc[4][4];
#pragma unroll
        for (int i = 0; i < 4; ++i)
#pragma unroll
            for (int j = 0; j < 4; ++j) acc[i][j] = zero;
#pragma unroll
        for (int kq = 0; kq < 4; ++kq) {
            const int ko = kq * 32 + lq * 8;
            bf16x8 af[4], bfr[4];
#pragma unroll
            for (int tm = 0; tm < 4; ++tm)
                af[tm] = as_frag(*(const int4*)(buf + sw_off(tm * 16 + lrow, ko)));
#pragma unroll
            for (int tn = 0; tn < 4; ++tn)
                bfr[tn] = as_frag(*(const int4*)(W1T + (size_t)(nbase + tn * 16 + lrow) * 128 + ko));
#pragma unroll
            for (int tm = 0; tm < 4; ++tm)
#pragma unroll
                for (int tn = 0; tn < 4; ++tn)
                    acc[tm][tn] = __builtin_amdgcn_mfma_f32_16x16x32_bf16(af[tm], bfr[tn], acc[tm][tn], 0, 0, 0);
        }
        __syncthreads();
#pragma unroll
        for (int tn = 0; tn < 4; ++tn) {
            const int n = nbase + tn * 16 + lrow;
            const float bias = b1[n];
#pragma unroll
            for (int tm = 0; tm < 4; ++tm)
#pragma unroll
                for (int r = 0; r < 4; ++r) {
                    const int m = tm * 16 + lq * 4 + r;
                    buf[sw_off(m, n)] = f2bf(fast_tanh(acc[tm][tn][r] + bias));
                }
        }
    }
    __syncthreads();

    // ---- layer 2: K=256 -> 256 cols
    {
        f32x4 acc[4][4];
#pragma unroll
        for (int i = 0; i < 4; ++i)
#pragma unroll
            for (int j = 0; j < 4; ++j) acc[i][j] = zero;
#pragma unroll
        for (int kq = 0; kq < 8; ++kq) {
            const int ko = kq * 32 + lq * 8;
            bf16x8 af[4], bfr[4];
#pragma unroll
            for (int tm = 0; tm < 4; ++tm)
                af[tm] = as_frag(*(const int4*)(buf + sw_off(tm * 16 + lrow, ko)));
#pragma unroll
            for (int tn = 0; tn < 4; ++tn)
                bfr[tn] = as_frag(*(const int4*)(W2T + (size_t)(nbase + tn * 16 + lrow) * 256 + ko));
#pragma unroll
            for (int tm = 0; tm < 4; ++tm)
#pragma unroll
                for (int tn = 0; tn < 4; ++tn)
                    acc[tm][tn] = __builtin_amdgcn_mfma_f32_16x16x32_bf16(af[tm], bfr[tn], acc[tm][tn], 0, 0, 0);
        }
        __syncthreads();
#pragma unroll
        for (int tn = 0; tn < 4; ++tn) {
            const int n = nbase + tn * 16 + lrow;
            const float bias = b2[n];
#pragma unroll
            for (int tm = 0; tm < 4; ++tm)
#pragma unroll
                for (int r = 0; r < 4; ++r) {
                    const int m = tm * 16 + lq * 4 + r;
                    buf[sw_off(m, n)] = f2bf(fast_tanh(acc[tm][tn][r] + bias));
                }
        }
    }
    __syncthreads();

    // ---- layer 3: 256 -> 1, 4 threads per id, shuffle reduce
    {
        const int m = t >> 2, p = t & 3;
        float s = 0.f;
#pragma unroll
        for (int i = 0; i < 64; ++i) {
            const int k = p * 64 + i;
            const float a = __uint_as_float((unsigned int)buf[sw_off(m, k)] << 16);
            s += a * W3[k];
        }
        s += __shfl_xor(s, 1);
        s += __shfl_xor(s, 2);
        if (p == 0) out[id0 + m] = s + b3[0];
    }
}

// ---------------------------------------------------------------- launch
extern "C" void kernel_launch(void* const* d_in, const int* in_sizes, int n_in,
                              void* d_out, int out_size, void* d_ws, size_t ws_size,
                              hipStream_t stream) {
    const float* obs    = (const float*)d_in[0];
    const int*   edges  = (const int*)  d_in[1];
    const float* enc_W  = (const float*)d_in[2];
    const float* enc_b  = (const float*)d_in[3];
    const float* msg_W1 = (const float*)d_in[4];
    const float* msg_b1 = (const float*)d_in[5];
    const float* msg_W2 = (const float*)d_in[6];
    const float* msg_b2 = (const float*)d_in[7];
    const float* msg_W3 = (const float*)d_in[8];
    const float* msg_b3 = (const float*)d_in[9];
    const float* gru_Wi = (const float*)d_in[10];
    const float* gru_Wh = (const float*)d_in[11];
    const float* gru_bi = (const float*)d_in[12];
    const float* gru_bh = (const float*)d_in[13];
    const float* dec_W1 = (const float*)d_in[14];
    const float* dec_b1 = (const float*)d_in[15];
    const float* dec_W2 = (const float*)d_in[16];
    const float* dec_b2 = (const float*)d_in[17];
    const float* dec_W3 = (const float*)d_in[18];
    const float* dec_b3 = (const float*)d_in[19];

    float* x       = (float*)d_ws;                 // BN*128 f32
    float* aggr    = x + (size_t)BN * H;           // BN*128 f32
    float* inv_deg = aggr + (size_t)BN * H;        // BN f32
    unsigned short* wbf = (unsigned short*)(inv_deg + BN);   // 1540096 bf16
    unsigned short* P   = wbf + 1540096;           // BN*512 bf16 (75.5 MB)

    deg_kernel<<<(BGR + 255) / 256, 256, 0, stream>>>(edges, inv_deg);
    wt_kernel<<<1540096 / 256, 256, 0, stream>>>(msg_W1, msg_W2, msg_W3, gru_Wi, gru_Wh,
                                                 dec_W1, dec_W2, wbf);
    enc_kernel<<<BN * H / 256, 256, 0, stream>>>(obs, enc_W, enc_b, x);

    // step-0 P + self-message
    proj_mfma<<<BN / 64, 512, 0, stream>>>(
        x, wbf + 1277952, msg_b1,
        wbf + 262144, msg_b2, wbf + 524288, P, aggr);

    for (int s = 0; s < 4; ++s) {
        const unsigned short* W2T = wbf + 262144 + (size_t)s * 65536;
        const unsigned short* W3T = wbf + 524288 + (size_t)s * 32768;
        const unsigned short* WGs = wbf + 655360 + (size_t)s * 131072;
        const int nx = (s < 3) ? s + 1 : s;
        const unsigned short* W1Pn = wbf + 1277952 + (size_t)nx * 65536;
        const unsigned short* W2Tn = wbf + 262144 + (size_t)nx * 65536;
        const unsigned short* W3Tn = wbf + 524288 + (size_t)nx * 32768;
        msg_mfma<<<NE / 64, 512, 0, stream>>>(
            P, edges,
            msg_b1 + (size_t)s * 256,
            W2T, msg_b2 + (size_t)s * 256,
            W3T,
            aggr);
        grup_mfma<<<BN / 64, 512, 0, stream>>>(
            x, aggr, inv_deg, WGs, msg_b3 + (size_t)s * 128,
            gru_bi + (size_t)s * 384, gru_bh + (size_t)s * 384,
            W1Pn, msg_b1 + (size_t)nx * 256,
            W2Tn, msg_b2 + (size_t)nx * 256,
            W3Tn,
            P, (s < 3) ? 1 : 0);
    }

    dec_mfma<<<BGR * 8 / 64, 256, 0, stream>>>(
        x, wbf + 1179648, dec_b1, wbf + 1212416, dec_b2, dec_W3, dec_b3, (float*)d_out);
}